// Round 3
// baseline (646.335 us; speedup 1.0000x reference)
//
#include <hip/hip_runtime.h>

#define Bb 16
#define Nn 200
#define NM1 199
#define Uu 64
#define EPSBN 1e-5f
#define SLOPE 0.01f
#define SPREAD 64
#define ETS 72   // f16 elems per Et row (64 + 8 pad)
#define ZS 68    // f32 elems per zbuf row (64 + 4 pad, keeps 16B alignment)

typedef _Float16 f16;
typedef __attribute__((ext_vector_type(8))) _Float16 f16x8;
typedef __attribute__((ext_vector_type(2))) _Float16 f16x2;
typedef __attribute__((ext_vector_type(4))) float floatx4;

__device__ __forceinline__ float lrelu(float v) { return v > 0.f ? v : SLOPE * v; }
__device__ __forceinline__ int dstcol(int n, int k) { return k < n ? k : k + 1; }
__device__ __forceinline__ float sigm(float v) { return 1.f / (1.f + __expf(-v)); }

__device__ __forceinline__ void stageEt(const float* __restrict__ ew, f16* Et, int tid) {
    int u = tid & 63, g = tid >> 6;
#pragma unroll
    for (int pp = 0; pp < 8; ++pp) {
        int jp = g + pp * 4;
        f16x2 pk;
        pk.x = (f16)ew[(2 * jp) * Uu + u];
        pk.y = (f16)ew[(2 * jp + 1) * Uu + u];
        *(f16x2*)&Et[u * ETS + 2 * jp] = pk;
    }
}

// x-vec projections; L0 also computes h from x; block 0 zeroes spread
template <bool L0>
__global__ void k_xvec(const float* __restrict__ xin, const float* __restrict__ l0w,
                       const float* __restrict__ l0b, float* __restrict__ h,
                       const float* __restrict__ w1, const float* __restrict__ b1,
                       const float* __restrict__ w2, const float* __restrict__ b2,
                       const float* __restrict__ w3, const float* __restrict__ b3,
                       const float* __restrict__ w4, const float* __restrict__ b4,
                       float* __restrict__ x1, float* __restrict__ x2,
                       float* __restrict__ x3, float* __restrict__ x4,
                       float* __restrict__ spread) {
    __shared__ float hrow[Uu];
    int bn = blockIdx.x;
    int u = threadIdx.x;
    if (blockIdx.x == 0) {
        for (int t = u; t < SPREAD * 128; t += Uu) spread[t] = 0.f;
    }
    if (L0) {
        float v = fmaf(xin[bn * 2], l0w[u], fmaf(xin[bn * 2 + 1], l0w[Uu + u], l0b[u]));
        v = lrelu(v);
        hrow[u] = v;
        h[bn * Uu + u] = v;
    } else {
        hrow[u] = h[bn * Uu + u];
    }
    __syncthreads();
    float a1 = b1[u], a2 = b2[u], a3 = b3[u], a4 = b4[u];
#pragma unroll 8
    for (int j = 0; j < Uu; ++j) {
        float hv = hrow[j];
        a1 = fmaf(hv, w1[j * Uu + u], a1);
        a2 = fmaf(hv, w2[j * Uu + u], a2);
        a3 = fmaf(hv, w3[j * Uu + u], a3);
        a4 = fmaf(hv, w4[j * Uu + u], a4);
    }
    x1[bn * Uu + u] = a1;
    x2[bn * Uu + u] = a2;
    x3[bn * Uu + u] = a3;
    x4[bn * Uu + u] = a4;
}

// layer-0 stats + pooled; w0 recomputed from adj, never stored
__global__ __launch_bounds__(256, 3) void k_first(
    const float* __restrict__ adj,
    const float* __restrict__ ew1, const float* __restrict__ eb1,
    const float* __restrict__ e0w, const float* __restrict__ e0b,
    const float* __restrict__ x2a, const float* __restrict__ x3a,
    const float* __restrict__ x4a,
    float* __restrict__ pooled, float* __restrict__ spread) {
    __shared__ __align__(16) f16 Et[Uu * ETS];
    __shared__ float c2s[Uu];
    __shared__ float sred[128];
    __shared__ float pbuf[4][Uu];
    int bn = blockIdx.x;
    int b = bn / Nn, n = bn % Nn;
    int tid = threadIdx.x;
    int l = tid & 63, wv = tid >> 6;
    int r16 = l & 15, q = l >> 4;
    stageEt(ew1, Et, tid);
    if (tid < Uu) c2s[tid] = eb1[tid] + x3a[(size_t)bn * Uu + tid];
    if (tid < 128) sred[tid] = 0.f;
    __syncthreads();

    float e0r[2][8], e0br[2][8];
#pragma unroll
    for (int g2 = 0; g2 < 2; ++g2)
#pragma unroll
        for (int j = 0; j < 8; ++j) {
            int ch = g2 * 32 + q * 8 + j;
            e0r[g2][j] = e0w[ch];
            e0br[g2][j] = e0b[ch];
        }
    f16x8 Bf[2][4];
#pragma unroll
    for (int hh = 0; hh < 2; ++hh)
#pragma unroll
        for (int nt = 0; nt < 4; ++nt)
            Bf[hh][nt] = *(const f16x8*)&Et[(nt * 16 + r16) * ETS + hh * 32 + q * 8];

    const float* adjrow = adj + (size_t)bn * Nn;
    float sum[4] = {0, 0, 0, 0}, sq[4] = {0, 0, 0, 0};
    float pm[2][8];
#pragma unroll
    for (int g2 = 0; g2 < 2; ++g2)
#pragma unroll
        for (int j = 0; j < 8; ++j) pm[g2][j] = -3.402823e38f;

    for (int mt = wv; mt < 13; mt += 4) {
        int row = mt * 16 + r16;
        bool rv = row < NM1;
        int dst = dstcol(n, rv ? row : 0);
        float adv = rv ? adjrow[dst] : 0.f;
        float w0[2][8];
        f16x8 A0, A1;
#pragma unroll
        for (int j = 0; j < 8; ++j) {
            w0[0][j] = lrelu(fmaf(adv, e0r[0][j], e0br[0][j]));
            w0[1][j] = lrelu(fmaf(adv, e0r[1][j], e0br[1][j]));
            A0[j] = (f16)w0[0][j];
            A1[j] = (f16)w0[1][j];
        }
        if (!rv) {
            A0 = (f16x8){0, 0, 0, 0, 0, 0, 0, 0};
            A1 = A0;
        }
        floatx4 acc[4];
#pragma unroll
        for (int nt = 0; nt < 4; ++nt) {
            acc[nt] = (floatx4){0, 0, 0, 0};
            acc[nt] = __builtin_amdgcn_mfma_f32_16x16x32_f16(A0, Bf[0][nt], acc[nt], 0, 0, 0);
            acc[nt] = __builtin_amdgcn_mfma_f32_16x16x32_f16(A1, Bf[1][nt], acc[nt], 0, 0, 0);
        }
#pragma unroll
        for (int rr = 0; rr < 4; ++rr) {
            int k = mt * 16 + q * 4 + rr;
            if (k < NM1) {
                int d2 = dstcol(n, k);
                const float* x4r = x4a + (size_t)(b * Nn + d2) * Uu;
#pragma unroll
                for (int nt = 0; nt < 4; ++nt) {
                    int u = nt * 16 + r16;
                    float z = acc[nt][rr] + c2s[u] + x4r[u];
                    sum[nt] += z;
                    sq[nt] = fmaf(z, z, sq[nt]);
                }
            }
        }
        if (rv) {
            const float* x2r = x2a + (size_t)(b * Nn + dst) * Uu;
#pragma unroll
            for (int g2 = 0; g2 < 2; ++g2) {
                float xv[8];
                *(float4*)&xv[0] = *(const float4*)(x2r + g2 * 32 + q * 8);
                *(float4*)&xv[4] = *(const float4*)(x2r + g2 * 32 + q * 8 + 4);
#pragma unroll
                for (int j = 0; j < 8; ++j)
                    pm[g2][j] = fmaxf(pm[g2][j], sigm(w0[g2][j]) * xv[j]);
            }
        }
    }
#pragma unroll
    for (int nt = 0; nt < 4; ++nt) {
        sum[nt] += __shfl_xor(sum[nt], 16, 64);
        sum[nt] += __shfl_xor(sum[nt], 32, 64);
        sq[nt] += __shfl_xor(sq[nt], 16, 64);
        sq[nt] += __shfl_xor(sq[nt], 32, 64);
    }
    if (l < 16) {
#pragma unroll
        for (int nt = 0; nt < 4; ++nt) {
            atomicAdd(&sred[nt * 16 + l], sum[nt]);
            atomicAdd(&sred[64 + nt * 16 + l], sq[nt]);
        }
    }
#pragma unroll
    for (int g2 = 0; g2 < 2; ++g2)
#pragma unroll
        for (int j = 0; j < 8; ++j) {
            float v = pm[g2][j];
            v = fmaxf(v, __shfl_xor(v, 1, 64));
            v = fmaxf(v, __shfl_xor(v, 2, 64));
            v = fmaxf(v, __shfl_xor(v, 4, 64));
            v = fmaxf(v, __shfl_xor(v, 8, 64));
            pm[g2][j] = v;
        }
    if (r16 == 0) {
#pragma unroll
        for (int g2 = 0; g2 < 2; ++g2)
#pragma unroll
            for (int j = 0; j < 8; ++j) pbuf[wv][g2 * 32 + q * 8 + j] = pm[g2][j];
    }
    __syncthreads();
    if (tid < 128) atomicAdd(&spread[(bn & (SPREAD - 1)) * 128 + tid], sred[tid]);
    if (tid < Uu)
        pooled[(size_t)bn * Uu + tid] =
            fmaxf(fmaxf(pbuf[0][tid], pbuf[1][tid]), fmaxf(pbuf[2][tid], pbuf[3][tid]));
}

// fused: apply BN(i)+residual -> wnew (f16 store) -> GEMM(i+1) stats (+pooled)
template <bool FIRST, bool POOL2>
__global__ __launch_bounds__(256, 3) void k_fused(
    const float* __restrict__ adj, f16* __restrict__ w16,
    const float* __restrict__ ew1, const float* __restrict__ eb1,
    const float* __restrict__ ew2, const float* __restrict__ eb2,
    const float* __restrict__ e0w, const float* __restrict__ e0b,
    const float* __restrict__ x3a, const float* __restrict__ x4a,
    const float* __restrict__ x2b, const float* __restrict__ x3b,
    const float* __restrict__ x4b, const float* __restrict__ wss,
    float* __restrict__ pooled, float* __restrict__ spread) {
    __shared__ __align__(16) f16 Et1[Uu * ETS];
    __shared__ __align__(16) f16 Et2[Uu * ETS];
    __shared__ __align__(16) float zbuf[4][16 * ZS];
    __shared__ float c1s[Uu], c2s[Uu];
    __shared__ float sred[128];
    __shared__ float pbuf[4][Uu];
    int bn = blockIdx.x;
    int b = bn / Nn, n = bn % Nn;
    int tid = threadIdx.x;
    int l = tid & 63, wv = tid >> 6;
    int r16 = l & 15, q = l >> 4;
    stageEt(ew1, Et1, tid);
    stageEt(ew2, Et2, tid);
    if (tid < Uu) {
        c1s[tid] = eb1[tid] + x3a[(size_t)bn * Uu + tid];
        c2s[tid] = eb2[tid] + x3b[(size_t)bn * Uu + tid];
    }
    if (tid < 128) sred[tid] = 0.f;
    __syncthreads();

    float ssc[2][8], ssh[2][8], c1r[2][8];
    float e0r[2][8], e0br[2][8];
#pragma unroll
    for (int g2 = 0; g2 < 2; ++g2)
#pragma unroll
        for (int j = 0; j < 8; ++j) {
            int ch = g2 * 32 + q * 8 + j;
            ssc[g2][j] = wss[ch];
            ssh[g2][j] = wss[64 + ch];
            c1r[g2][j] = c1s[ch];
            if (FIRST) {
                e0r[g2][j] = e0w[ch];
                e0br[g2][j] = e0b[ch];
            }
        }

    const float* adjrow = adj + (size_t)bn * Nn;
    float sum[4] = {0, 0, 0, 0}, sq[4] = {0, 0, 0, 0};
    float pm[2][8];
#pragma unroll
    for (int g2 = 0; g2 < 2; ++g2)
#pragma unroll
        for (int j = 0; j < 8; ++j) pm[g2][j] = -3.402823e38f;
    float* zb = zbuf[wv];

    for (int mt = wv; mt < 13; mt += 4) {
        int row = mt * 16 + r16;
        bool rv = row < NM1;
        int dst = dstcol(n, rv ? row : 0);
        f16x8 A0, A1;
        float wold[2][8];
        if (FIRST) {
            float adv = rv ? adjrow[dst] : 0.f;
#pragma unroll
            for (int j = 0; j < 8; ++j) {
                wold[0][j] = lrelu(fmaf(adv, e0r[0][j], e0br[0][j]));
                wold[1][j] = lrelu(fmaf(adv, e0r[1][j], e0br[1][j]));
                A0[j] = (f16)wold[0][j];
                A1[j] = (f16)wold[1][j];
            }
            if (!rv) {
                A0 = (f16x8){0, 0, 0, 0, 0, 0, 0, 0};
                A1 = A0;
            }
        } else {
            size_t off = ((size_t)bn * NM1 + (rv ? row : 0)) * Uu;
            A0 = *(const f16x8*)(w16 + off + q * 8);
            A1 = *(const f16x8*)(w16 + off + 32 + q * 8);
            if (!rv) {
                A0 = (f16x8){0, 0, 0, 0, 0, 0, 0, 0};
                A1 = A0;
            }
#pragma unroll
            for (int j = 0; j < 8; ++j) {
                wold[0][j] = (float)A0[j];
                wold[1][j] = (float)A1[j];
            }
        }
        // GEMM(i): z pre-adds
        floatx4 acc[4];
#pragma unroll
        for (int nt = 0; nt < 4; ++nt) {
            f16x8 B0 = *(const f16x8*)&Et1[(nt * 16 + r16) * ETS + q * 8];
            f16x8 B1 = *(const f16x8*)&Et1[(nt * 16 + r16) * ETS + 32 + q * 8];
            acc[nt] = (floatx4){0, 0, 0, 0};
            acc[nt] = __builtin_amdgcn_mfma_f32_16x16x32_f16(A0, B0, acc[nt], 0, 0, 0);
            acc[nt] = __builtin_amdgcn_mfma_f32_16x16x32_f16(A1, B1, acc[nt], 0, 0, 0);
        }
        // C -> A transform through wave-private LDS
#pragma unroll
        for (int rr = 0; rr < 4; ++rr) {
            int zr = q * 4 + rr;
#pragma unroll
            for (int nt = 0; nt < 4; ++nt) zb[zr * ZS + nt * 16 + r16] = acc[nt][rr];
        }
        float zA[2][8];
        *(float4*)&zA[0][0] = *(const float4*)&zb[r16 * ZS + q * 8];
        *(float4*)&zA[0][4] = *(const float4*)&zb[r16 * ZS + q * 8 + 4];
        *(float4*)&zA[1][0] = *(const float4*)&zb[r16 * ZS + 32 + q * 8];
        *(float4*)&zA[1][4] = *(const float4*)&zb[r16 * ZS + 32 + q * 8 + 4];
        // BN apply + residual (A layout)
        float x4v[2][8] = {{0, 0, 0, 0, 0, 0, 0, 0}, {0, 0, 0, 0, 0, 0, 0, 0}};
        if (rv) {
            const float* x4r = x4a + (size_t)(b * Nn + dst) * Uu;
            *(float4*)&x4v[0][0] = *(const float4*)(x4r + q * 8);
            *(float4*)&x4v[0][4] = *(const float4*)(x4r + q * 8 + 4);
            *(float4*)&x4v[1][0] = *(const float4*)(x4r + 32 + q * 8);
            *(float4*)&x4v[1][4] = *(const float4*)(x4r + 32 + q * 8 + 4);
        }
        float wnewf[2][8];
        f16x8 W0, W1;
#pragma unroll
        for (int g2 = 0; g2 < 2; ++g2)
#pragma unroll
            for (int j = 0; j < 8; ++j) {
                float z = zA[g2][j] + c1r[g2][j] + x4v[g2][j];
                wnewf[g2][j] = wold[g2][j] + lrelu(fmaf(z, ssc[g2][j], ssh[g2][j]));
            }
#pragma unroll
        for (int j = 0; j < 8; ++j) {
            W0[j] = (f16)wnewf[0][j];
            W1[j] = (f16)wnewf[1][j];
        }
        if (rv) {
            size_t off = ((size_t)bn * NM1 + row) * Uu;
            *(f16x8*)(w16 + off + q * 8) = W0;
            *(f16x8*)(w16 + off + 32 + q * 8) = W1;
        }
        if (POOL2 && rv) {
            const float* x2r = x2b + (size_t)(b * Nn + dst) * Uu;
#pragma unroll
            for (int g2 = 0; g2 < 2; ++g2) {
                float xv[8];
                *(float4*)&xv[0] = *(const float4*)(x2r + g2 * 32 + q * 8);
                *(float4*)&xv[4] = *(const float4*)(x2r + g2 * 32 + q * 8 + 4);
#pragma unroll
                for (int j = 0; j < 8; ++j)
                    pm[g2][j] = fmaxf(pm[g2][j], sigm(wnewf[g2][j]) * xv[j]);
            }
        }
        // GEMM(i+1) for stats
        floatx4 acc2[4];
#pragma unroll
        for (int nt = 0; nt < 4; ++nt) {
            f16x8 B0 = *(const f16x8*)&Et2[(nt * 16 + r16) * ETS + q * 8];
            f16x8 B1 = *(const f16x8*)&Et2[(nt * 16 + r16) * ETS + 32 + q * 8];
            acc2[nt] = (floatx4){0, 0, 0, 0};
            acc2[nt] = __builtin_amdgcn_mfma_f32_16x16x32_f16(W0, B0, acc2[nt], 0, 0, 0);
            acc2[nt] = __builtin_amdgcn_mfma_f32_16x16x32_f16(W1, B1, acc2[nt], 0, 0, 0);
        }
#pragma unroll
        for (int rr = 0; rr < 4; ++rr) {
            int k = mt * 16 + q * 4 + rr;
            if (k < NM1) {
                int d2 = dstcol(n, k);
                const float* x4r = x4b + (size_t)(b * Nn + d2) * Uu;
#pragma unroll
                for (int nt = 0; nt < 4; ++nt) {
                    int u = nt * 16 + r16;
                    float z = acc2[nt][rr] + c2s[u] + x4r[u];
                    sum[nt] += z;
                    sq[nt] = fmaf(z, z, sq[nt]);
                }
            }
        }
    }
#pragma unroll
    for (int nt = 0; nt < 4; ++nt) {
        sum[nt] += __shfl_xor(sum[nt], 16, 64);
        sum[nt] += __shfl_xor(sum[nt], 32, 64);
        sq[nt] += __shfl_xor(sq[nt], 16, 64);
        sq[nt] += __shfl_xor(sq[nt], 32, 64);
    }
    if (l < 16) {
#pragma unroll
        for (int nt = 0; nt < 4; ++nt) {
            atomicAdd(&sred[nt * 16 + l], sum[nt]);
            atomicAdd(&sred[64 + nt * 16 + l], sq[nt]);
        }
    }
    if (POOL2) {
#pragma unroll
        for (int g2 = 0; g2 < 2; ++g2)
#pragma unroll
            for (int j = 0; j < 8; ++j) {
                float v = pm[g2][j];
                v = fmaxf(v, __shfl_xor(v, 1, 64));
                v = fmaxf(v, __shfl_xor(v, 2, 64));
                v = fmaxf(v, __shfl_xor(v, 4, 64));
                v = fmaxf(v, __shfl_xor(v, 8, 64));
                pm[g2][j] = v;
            }
        if (r16 == 0) {
#pragma unroll
            for (int g2 = 0; g2 < 2; ++g2)
#pragma unroll
                for (int j = 0; j < 8; ++j) pbuf[wv][g2 * 32 + q * 8 + j] = pm[g2][j];
        }
    }
    __syncthreads();
    if (tid < 128) atomicAdd(&spread[(bn & (SPREAD - 1)) * 128 + tid], sred[tid]);
    if (POOL2 && tid < Uu)
        pooled[(size_t)bn * Uu + tid] =
            fmaxf(fmaxf(pbuf[0][tid], pbuf[1][tid]), fmaxf(pbuf[2][tid], pbuf[3][tid]));
}

// last: apply BN(2)+residual, dot with e_lin1, scatter to out
__global__ __launch_bounds__(256, 3) void k_last(
    const f16* __restrict__ w16, const float* __restrict__ ew1,
    const float* __restrict__ eb1, const float* __restrict__ x3a,
    const float* __restrict__ x4a, const float* __restrict__ wss,
    const float* __restrict__ elw, const float* __restrict__ elb,
    float* __restrict__ out) {
    __shared__ __align__(16) f16 Et1[Uu * ETS];
    __shared__ __align__(16) float zbuf[4][16 * ZS];
    __shared__ float c1s[Uu];
    int bn = blockIdx.x;
    int b = bn / Nn, n = bn % Nn;
    int tid = threadIdx.x;
    int l = tid & 63, wv = tid >> 6;
    int r16 = l & 15, q = l >> 4;
    stageEt(ew1, Et1, tid);
    if (tid < Uu) c1s[tid] = eb1[tid] + x3a[(size_t)bn * Uu + tid];
    __syncthreads();

    float ssc[2][8], ssh[2][8], c1r[2][8], elr[2][8];
#pragma unroll
    for (int g2 = 0; g2 < 2; ++g2)
#pragma unroll
        for (int j = 0; j < 8; ++j) {
            int ch = g2 * 32 + q * 8 + j;
            ssc[g2][j] = wss[ch];
            ssh[g2][j] = wss[64 + ch];
            c1r[g2][j] = c1s[ch];
            elr[g2][j] = elw[ch];
        }
    float elb0 = elb[0];
    f16x8 Bf[2][4];
#pragma unroll
    for (int hh = 0; hh < 2; ++hh)
#pragma unroll
        for (int nt = 0; nt < 4; ++nt)
            Bf[hh][nt] = *(const f16x8*)&Et1[(nt * 16 + r16) * ETS + hh * 32 + q * 8];
    float* zb = zbuf[wv];

    for (int mt = wv; mt < 13; mt += 4) {
        int row = mt * 16 + r16;
        bool rv = row < NM1;
        int dst = dstcol(n, rv ? row : 0);
        size_t off = ((size_t)bn * NM1 + (rv ? row : 0)) * Uu;
        f16x8 A0 = *(const f16x8*)(w16 + off + q * 8);
        f16x8 A1 = *(const f16x8*)(w16 + off + 32 + q * 8);
        if (!rv) {
            A0 = (f16x8){0, 0, 0, 0, 0, 0, 0, 0};
            A1 = A0;
        }
        float wold[2][8];
#pragma unroll
        for (int j = 0; j < 8; ++j) {
            wold[0][j] = (float)A0[j];
            wold[1][j] = (float)A1[j];
        }
        floatx4 acc[4];
#pragma unroll
        for (int nt = 0; nt < 4; ++nt) {
            acc[nt] = (floatx4){0, 0, 0, 0};
            acc[nt] = __builtin_amdgcn_mfma_f32_16x16x32_f16(A0, Bf[0][nt], acc[nt], 0, 0, 0);
            acc[nt] = __builtin_amdgcn_mfma_f32_16x16x32_f16(A1, Bf[1][nt], acc[nt], 0, 0, 0);
        }
#pragma unroll
        for (int rr = 0; rr < 4; ++rr) {
            int zr = q * 4 + rr;
#pragma unroll
            for (int nt = 0; nt < 4; ++nt) zb[zr * ZS + nt * 16 + r16] = acc[nt][rr];
        }
        float zA[2][8];
        *(float4*)&zA[0][0] = *(const float4*)&zb[r16 * ZS + q * 8];
        *(float4*)&zA[0][4] = *(const float4*)&zb[r16 * ZS + q * 8 + 4];
        *(float4*)&zA[1][0] = *(const float4*)&zb[r16 * ZS + 32 + q * 8];
        *(float4*)&zA[1][4] = *(const float4*)&zb[r16 * ZS + 32 + q * 8 + 4];
        float x4v[2][8] = {{0, 0, 0, 0, 0, 0, 0, 0}, {0, 0, 0, 0, 0, 0, 0, 0}};
        if (rv) {
            const float* x4r = x4a + (size_t)(b * Nn + dst) * Uu;
            *(float4*)&x4v[0][0] = *(const float4*)(x4r + q * 8);
            *(float4*)&x4v[0][4] = *(const float4*)(x4r + q * 8 + 4);
            *(float4*)&x4v[1][0] = *(const float4*)(x4r + 32 + q * 8);
            *(float4*)&x4v[1][4] = *(const float4*)(x4r + 32 + q * 8 + 4);
        }
        float t = 0.f;
#pragma unroll
        for (int g2 = 0; g2 < 2; ++g2)
#pragma unroll
            for (int j = 0; j < 8; ++j) {
                float z = zA[g2][j] + c1r[g2][j] + x4v[g2][j];
                float wn = wold[g2][j] + lrelu(fmaf(z, ssc[g2][j], ssh[g2][j]));
                t = fmaf(wn, elr[g2][j], t);
            }
        t += __shfl_xor(t, 16, 64);
        t += __shfl_xor(t, 32, 64);
        if (q == 0 && rv) out[(size_t)bn * Nn + dst] = t + elb0;
    }
    if (tid == 0) out[(size_t)bn * Nn + n] = 0.f;
}

// finw (block 64) + hup (blocks 0..63)
__global__ void k_mid(const float* __restrict__ spread, const float* __restrict__ eg,
                      const float* __restrict__ ebb, float* __restrict__ wss,
                      const float* __restrict__ x1, const float* __restrict__ pooled,
                      const float* __restrict__ vg, const float* __restrict__ vbb,
                      float* __restrict__ h) {
    if (blockIdx.x == 64) {
        int u = threadIdx.x;
        if (u < 64) {
            float s = 0.f, sqv = 0.f;
            for (int p = 0; p < SPREAD; ++p) {
                s += spread[p * 128 + u];
                sqv += spread[p * 128 + 64 + u];
            }
            const float Mf = (float)((size_t)Bb * Nn * NM1);
            float mean = s / Mf;
            float var = fmaxf(sqv / Mf - mean * mean, 0.f);
            float inv = rsqrtf(var + EPSBN);
            float scale = eg[u] * inv;
            wss[u] = scale;
            wss[64 + u] = ebb[u] - mean * scale;
        }
        return;
    }
    __shared__ float red[256], red2[256];
    int ch = blockIdx.x;
    int t = threadIdx.x;
    float s = 0.f, sqv = 0.f;
    for (int bn = t; bn < Bb * Nn; bn += 256) {
        float v = x1[bn * Uu + ch] + pooled[bn * Uu + ch];
        s += v;
        sqv = fmaf(v, v, sqv);
    }
    red[t] = s;
    red2[t] = sqv;
    __syncthreads();
    for (int off = 128; off; off >>= 1) {
        if (t < off) {
            red[t] += red[t + off];
            red2[t] += red2[t + off];
        }
        __syncthreads();
    }
    const float Mf = (float)(Bb * Nn);
    float mean = red[0] / Mf;
    float var = fmaxf(red2[0] / Mf - mean * mean, 0.f);
    float inv = rsqrtf(var + EPSBN);
    float scale = vg[ch] * inv;
    float shift = vbb[ch] - mean * scale;
    for (int bn = t; bn < Bb * Nn; bn += 256) {
        float v = x1[bn * Uu + ch] + pooled[bn * Uu + ch];
        h[bn * Uu + ch] += lrelu(fmaf(v, scale, shift));
    }
}

__global__ void k_finw(const float* __restrict__ spread, const float* __restrict__ g,
                       const float* __restrict__ bb, float* __restrict__ wss) {
    int u = threadIdx.x;
    float s = 0.f, sq = 0.f;
    for (int p = 0; p < SPREAD; ++p) {
        s += spread[p * 128 + u];
        sq += spread[p * 128 + 64 + u];
    }
    const float Mf = (float)((size_t)Bb * Nn * NM1);
    float mean = s / Mf;
    float var = fmaxf(sq / Mf - mean * mean, 0.f);
    float inv = rsqrtf(var + EPSBN);
    float scale = g[u] * inv;
    wss[u] = scale;
    wss[64 + u] = bb[u] - mean * scale;
}

extern "C" void kernel_launch(void* const* d_in, const int* in_sizes, int n_in,
                              void* d_out, int out_size, void* d_ws, size_t ws_size,
                              hipStream_t stream) {
    const float* x = (const float*)d_in[0];
    const float* adj = (const float*)d_in[1];
    const float* vl0w = (const float*)d_in[2];
    const float* vl0b = (const float*)d_in[3];
    const float* vw1 = (const float*)d_in[4];
    const float* vb1 = (const float*)d_in[5];
    const float* vw2 = (const float*)d_in[6];
    const float* vb2 = (const float*)d_in[7];
    const float* vw3 = (const float*)d_in[8];
    const float* vb3 = (const float*)d_in[9];
    const float* vw4 = (const float*)d_in[10];
    const float* vb4 = (const float*)d_in[11];
    const float* vbng = (const float*)d_in[12];
    const float* vbnb = (const float*)d_in[13];
    const float* e0w = (const float*)d_in[14];
    const float* e0b = (const float*)d_in[15];
    const float* ew = (const float*)d_in[16];
    const float* eb = (const float*)d_in[17];
    const float* ebng = (const float*)d_in[18];
    const float* ebnb = (const float*)d_in[19];
    const float* elw = (const float*)d_in[20];
    const float* elb = (const float*)d_in[21];
    float* out = (float*)d_out;

    f16* w16 = (f16*)d_ws;                      // 40,755,200 f16
    float* fb = (float*)d_ws + 20377600;
    const size_t NV = 204800;
    float* h = fb;
    float* xv1[3] = {fb + NV, fb + 2 * NV, fb + 3 * NV};
    float* xv2[3] = {fb + 4 * NV, fb + 5 * NV, fb + 6 * NV};
    float* xv3[3] = {fb + 7 * NV, fb + 8 * NV, fb + 9 * NV};
    float* xv4[3] = {fb + 10 * NV, fb + 11 * NV, fb + 12 * NV};
    float* pooled = fb + 13 * NV;
    float* spread = fb + 14 * NV;               // SPREAD*128
    float* wss = spread + SPREAD * 128;         // 128

    const int GRID = Bb * Nn;  // 3200

    k_xvec<true><<<GRID, 64, 0, stream>>>(x, vl0w, vl0b, h, vw1, vb1, vw2, vb2, vw3,
                                          vb3, vw4, vb4, xv1[0], xv2[0], xv3[0],
                                          xv4[0], spread);
    k_first<<<GRID, 256, 0, stream>>>(adj, ew, eb, e0w, e0b, xv2[0], xv3[0], xv4[0],
                                      pooled, spread);
    k_mid<<<65, 256, 0, stream>>>(spread, ebng, ebnb, wss, xv1[0], pooled, vbng,
                                  vbnb, h);
    k_xvec<false><<<GRID, 64, 0, stream>>>(x, vl0w, vl0b, h, vw1 + 4096, vb1 + 64,
                                           vw2 + 4096, vb2 + 64, vw3 + 4096, vb3 + 64,
                                           vw4 + 4096, vb4 + 64, xv1[1], xv2[1],
                                           xv3[1], xv4[1], spread);
    k_fused<true, true><<<GRID, 256, 0, stream>>>(
        adj, w16, ew, eb, ew + 4096, eb + 64, e0w, e0b, xv3[0], xv4[0], xv2[1],
        xv3[1], xv4[1], wss, pooled, spread);
    k_mid<<<65, 256, 0, stream>>>(spread, ebng + 64, ebnb + 64, wss, xv1[1], pooled,
                                  vbng + 64, vbnb + 64, h);
    k_xvec<false><<<GRID, 64, 0, stream>>>(x, vl0w, vl0b, h, vw1 + 8192, vb1 + 128,
                                           vw2 + 8192, vb2 + 128, vw3 + 8192,
                                           vb3 + 128, vw4 + 8192, vb4 + 128, xv1[2],
                                           xv2[2], xv3[2], xv4[2], spread);
    k_fused<false, false><<<GRID, 256, 0, stream>>>(
        adj, w16, ew + 4096, eb + 64, ew + 8192, eb + 128, e0w, e0b, xv3[1], xv4[1],
        xv2[2], xv3[2], xv4[2], wss, pooled, spread);
    k_finw<<<1, 64, 0, stream>>>(spread, ebng + 128, ebnb + 128, wss);
    k_last<<<GRID, 256, 0, stream>>>(w16, ew + 8192, eb + 128, xv3[2], xv4[2], wss,
                                     elw, elb, out);
}

// Round 4
// 631.249 us; speedup vs baseline: 1.0239x; 1.0239x over previous
//
#include <hip/hip_runtime.h>

#define Bb 16
#define Nn 200
#define NM1 199
#define Uu 64
#define EPSBN 1e-5f
#define SLOPE 0.01f
#define SPREAD 64
#define ETS 72   // f16 elems per Et row (64 + 8 pad)
#define ZS 68    // f32 elems per zbuf row (64 + 4 pad, keeps 16B alignment)

typedef _Float16 f16;
typedef __attribute__((ext_vector_type(8))) _Float16 f16x8;
typedef __attribute__((ext_vector_type(2))) _Float16 f16x2;
typedef __attribute__((ext_vector_type(4))) float floatx4;

// w16 tile layout: per (bn, mt) a 1024-f16 tile; chunk c (8 f16 = 16 B) holds
// channels (c>>4)*8..+7 of row (c&15) for chans 0..31 in KB0, 32..63 in KB1.
// Lane l's A-fragment == chunk l -> stores/loads are wave-contiguous 1 KB.
__device__ __forceinline__ size_t tbase(int bn, int mt) {
    return ((size_t)bn * 13 + mt) * 1024;
}

__device__ __forceinline__ float lrelu(float v) { return v > 0.f ? v : SLOPE * v; }
__device__ __forceinline__ int dstcol(int n, int k) { return k < n ? k : k + 1; }
__device__ __forceinline__ float sigm(float v) { return 1.f / (1.f + __expf(-v)); }

__device__ __forceinline__ void stageEt(const float* __restrict__ ew, f16* Et, int tid) {
    int u = tid & 63, g = tid >> 6;
#pragma unroll
    for (int pp = 0; pp < 8; ++pp) {
        int jp = g + pp * 4;
        f16x2 pk;
        pk.x = (f16)ew[(2 * jp) * Uu + u];
        pk.y = (f16)ew[(2 * jp + 1) * Uu + u];
        *(f16x2*)&Et[u * ETS + 2 * jp] = pk;
    }
}

// x-vec projections; L0 also computes h from x; block 0 zeroes spread
template <bool L0>
__global__ void k_xvec(const float* __restrict__ xin, const float* __restrict__ l0w,
                       const float* __restrict__ l0b, float* __restrict__ h,
                       const float* __restrict__ w1, const float* __restrict__ b1,
                       const float* __restrict__ w2, const float* __restrict__ b2,
                       const float* __restrict__ w3, const float* __restrict__ b3,
                       const float* __restrict__ w4, const float* __restrict__ b4,
                       float* __restrict__ x1, float* __restrict__ x2,
                       float* __restrict__ x3, float* __restrict__ x4,
                       float* __restrict__ spread) {
    __shared__ float hrow[Uu];
    int bn = blockIdx.x;
    int u = threadIdx.x;
    if (blockIdx.x == 0) {
        for (int t = u; t < SPREAD * 128; t += Uu) spread[t] = 0.f;
    }
    if (L0) {
        float v = fmaf(xin[bn * 2], l0w[u], fmaf(xin[bn * 2 + 1], l0w[Uu + u], l0b[u]));
        v = lrelu(v);
        hrow[u] = v;
        h[bn * Uu + u] = v;
    } else {
        hrow[u] = h[bn * Uu + u];
    }
    __syncthreads();
    float a1 = b1[u], a2 = b2[u], a3 = b3[u], a4 = b4[u];
#pragma unroll 8
    for (int j = 0; j < Uu; ++j) {
        float hv = hrow[j];
        a1 = fmaf(hv, w1[j * Uu + u], a1);
        a2 = fmaf(hv, w2[j * Uu + u], a2);
        a3 = fmaf(hv, w3[j * Uu + u], a3);
        a4 = fmaf(hv, w4[j * Uu + u], a4);
    }
    x1[bn * Uu + u] = a1;
    x2[bn * Uu + u] = a2;
    x3[bn * Uu + u] = a3;
    x4[bn * Uu + u] = a4;
}

// layer-0 stats + pooled; w0 recomputed from adj, never stored
__global__ __launch_bounds__(256, 3) void k_first(
    const float* __restrict__ adj,
    const float* __restrict__ ew1, const float* __restrict__ eb1,
    const float* __restrict__ e0w, const float* __restrict__ e0b,
    const float* __restrict__ x2a, const float* __restrict__ x3a,
    const float* __restrict__ x4a,
    float* __restrict__ pooled, float* __restrict__ spread) {
    __shared__ __align__(16) f16 Et[Uu * ETS];
    __shared__ float c2s[Uu];
    __shared__ float sred[128];
    __shared__ float pbuf[4][Uu];
    int bn = blockIdx.x;
    int b = bn / Nn, n = bn % Nn;
    int tid = threadIdx.x;
    int l = tid & 63, wv = tid >> 6;
    int r16 = l & 15, q = l >> 4;
    stageEt(ew1, Et, tid);
    if (tid < Uu) c2s[tid] = eb1[tid] + x3a[(size_t)bn * Uu + tid];
    if (tid < 128) sred[tid] = 0.f;
    __syncthreads();

    float e0r[2][8], e0br[2][8];
#pragma unroll
    for (int g2 = 0; g2 < 2; ++g2)
#pragma unroll
        for (int j = 0; j < 8; ++j) {
            int ch = g2 * 32 + q * 8 + j;
            e0r[g2][j] = e0w[ch];
            e0br[g2][j] = e0b[ch];
        }
    f16x8 Bf[2][4];
#pragma unroll
    for (int hh = 0; hh < 2; ++hh)
#pragma unroll
        for (int nt = 0; nt < 4; ++nt)
            Bf[hh][nt] = *(const f16x8*)&Et[(nt * 16 + r16) * ETS + hh * 32 + q * 8];

    const float* adjrow = adj + (size_t)bn * Nn;
    float sum[4] = {0, 0, 0, 0}, sq[4] = {0, 0, 0, 0};
    float pm[2][8];
#pragma unroll
    for (int g2 = 0; g2 < 2; ++g2)
#pragma unroll
        for (int j = 0; j < 8; ++j) pm[g2][j] = -3.402823e38f;

    for (int mt = wv; mt < 13; mt += 4) {
        int row = mt * 16 + r16;
        bool rv = row < NM1;
        int dst = dstcol(n, rv ? row : 0);
        float adv = rv ? adjrow[dst] : 0.f;
        float w0[2][8];
        f16x8 A0, A1;
#pragma unroll
        for (int j = 0; j < 8; ++j) {
            w0[0][j] = lrelu(fmaf(adv, e0r[0][j], e0br[0][j]));
            w0[1][j] = lrelu(fmaf(adv, e0r[1][j], e0br[1][j]));
            A0[j] = (f16)w0[0][j];
            A1[j] = (f16)w0[1][j];
        }
        if (!rv) {
            A0 = (f16x8){0, 0, 0, 0, 0, 0, 0, 0};
            A1 = A0;
        }
        floatx4 acc[4];
#pragma unroll
        for (int nt = 0; nt < 4; ++nt) {
            acc[nt] = (floatx4){0, 0, 0, 0};
            acc[nt] = __builtin_amdgcn_mfma_f32_16x16x32_f16(A0, Bf[0][nt], acc[nt], 0, 0, 0);
            acc[nt] = __builtin_amdgcn_mfma_f32_16x16x32_f16(A1, Bf[1][nt], acc[nt], 0, 0, 0);
        }
#pragma unroll
        for (int rr = 0; rr < 4; ++rr) {
            int k = mt * 16 + q * 4 + rr;
            if (k < NM1) {
                int d2 = dstcol(n, k);
                const float* x4r = x4a + (size_t)(b * Nn + d2) * Uu;
#pragma unroll
                for (int nt = 0; nt < 4; ++nt) {
                    int u = nt * 16 + r16;
                    float z = acc[nt][rr] + c2s[u] + x4r[u];
                    sum[nt] += z;
                    sq[nt] = fmaf(z, z, sq[nt]);
                }
            }
        }
        if (rv) {
            const float* x2r = x2a + (size_t)(b * Nn + dst) * Uu;
#pragma unroll
            for (int g2 = 0; g2 < 2; ++g2) {
                float xv[8];
                *(float4*)&xv[0] = *(const float4*)(x2r + g2 * 32 + q * 8);
                *(float4*)&xv[4] = *(const float4*)(x2r + g2 * 32 + q * 8 + 4);
#pragma unroll
                for (int j = 0; j < 8; ++j)
                    pm[g2][j] = fmaxf(pm[g2][j], sigm(w0[g2][j]) * xv[j]);
            }
        }
    }
#pragma unroll
    for (int nt = 0; nt < 4; ++nt) {
        sum[nt] += __shfl_xor(sum[nt], 16, 64);
        sum[nt] += __shfl_xor(sum[nt], 32, 64);
        sq[nt] += __shfl_xor(sq[nt], 16, 64);
        sq[nt] += __shfl_xor(sq[nt], 32, 64);
    }
    if (l < 16) {
#pragma unroll
        for (int nt = 0; nt < 4; ++nt) {
            atomicAdd(&sred[nt * 16 + l], sum[nt]);
            atomicAdd(&sred[64 + nt * 16 + l], sq[nt]);
        }
    }
#pragma unroll
    for (int g2 = 0; g2 < 2; ++g2)
#pragma unroll
        for (int j = 0; j < 8; ++j) {
            float v = pm[g2][j];
            v = fmaxf(v, __shfl_xor(v, 1, 64));
            v = fmaxf(v, __shfl_xor(v, 2, 64));
            v = fmaxf(v, __shfl_xor(v, 4, 64));
            v = fmaxf(v, __shfl_xor(v, 8, 64));
            pm[g2][j] = v;
        }
    if (r16 == 0) {
#pragma unroll
        for (int g2 = 0; g2 < 2; ++g2)
#pragma unroll
            for (int j = 0; j < 8; ++j) pbuf[wv][g2 * 32 + q * 8 + j] = pm[g2][j];
    }
    __syncthreads();
    if (tid < 128) atomicAdd(&spread[(bn & (SPREAD - 1)) * 128 + tid], sred[tid]);
    if (tid < Uu)
        pooled[(size_t)bn * Uu + tid] =
            fmaxf(fmaxf(pbuf[0][tid], pbuf[1][tid]), fmaxf(pbuf[2][tid], pbuf[3][tid]));
}

// fused: apply BN(i)+residual -> wnew (tile-layout f16 store) -> GEMM(i+1) stats (+pooled)
template <bool FIRST, bool POOL2>
__global__ __launch_bounds__(256, 3) void k_fused(
    const float* __restrict__ adj, f16* __restrict__ w16,
    const float* __restrict__ ew1, const float* __restrict__ eb1,
    const float* __restrict__ ew2, const float* __restrict__ eb2,
    const float* __restrict__ e0w, const float* __restrict__ e0b,
    const float* __restrict__ x3a, const float* __restrict__ x4a,
    const float* __restrict__ x2b, const float* __restrict__ x3b,
    const float* __restrict__ x4b, const float* __restrict__ wss,
    float* __restrict__ pooled, float* __restrict__ spread) {
    __shared__ __align__(16) f16 Et1[Uu * ETS];
    __shared__ __align__(16) f16 Et2[Uu * ETS];
    __shared__ __align__(16) float zbuf[4][16 * ZS];
    __shared__ float c1s[Uu], c2s[Uu];
    __shared__ float sred[128];
    __shared__ float pbuf[4][Uu];
    int bn = blockIdx.x;
    int b = bn / Nn, n = bn % Nn;
    int tid = threadIdx.x;
    int l = tid & 63, wv = tid >> 6;
    int r16 = l & 15, q = l >> 4;
    stageEt(ew1, Et1, tid);
    stageEt(ew2, Et2, tid);
    if (tid < Uu) {
        c1s[tid] = eb1[tid] + x3a[(size_t)bn * Uu + tid];
        c2s[tid] = eb2[tid] + x3b[(size_t)bn * Uu + tid];
    }
    if (tid < 128) sred[tid] = 0.f;
    __syncthreads();

    float ssc[2][8], ssh[2][8], c1r[2][8];
    float e0r[2][8], e0br[2][8];
#pragma unroll
    for (int g2 = 0; g2 < 2; ++g2)
#pragma unroll
        for (int j = 0; j < 8; ++j) {
            int ch = g2 * 32 + q * 8 + j;
            ssc[g2][j] = wss[ch];
            ssh[g2][j] = wss[64 + ch];
            c1r[g2][j] = c1s[ch];
            if (FIRST) {
                e0r[g2][j] = e0w[ch];
                e0br[g2][j] = e0b[ch];
            }
        }

    const float* adjrow = adj + (size_t)bn * Nn;
    float sum[4] = {0, 0, 0, 0}, sq[4] = {0, 0, 0, 0};
    float pm[2][8];
#pragma unroll
    for (int g2 = 0; g2 < 2; ++g2)
#pragma unroll
        for (int j = 0; j < 8; ++j) pm[g2][j] = -3.402823e38f;
    float* zb = zbuf[wv];

    for (int mt = wv; mt < 13; mt += 4) {
        int row = mt * 16 + r16;
        bool rv = row < NM1;
        int dst = dstcol(n, rv ? row : 0);
        size_t tb = tbase(bn, mt);
        f16x8 A0, A1;
        float wold[2][8];
        if (FIRST) {
            float adv = rv ? adjrow[dst] : 0.f;
#pragma unroll
            for (int j = 0; j < 8; ++j) {
                wold[0][j] = lrelu(fmaf(adv, e0r[0][j], e0br[0][j]));
                wold[1][j] = lrelu(fmaf(adv, e0r[1][j], e0br[1][j]));
                A0[j] = (f16)wold[0][j];
                A1[j] = (f16)wold[1][j];
            }
            if (!rv) {
                A0 = (f16x8){0, 0, 0, 0, 0, 0, 0, 0};
                A1 = A0;
            }
        } else {
            // tile-layout load: lane l's fragment == chunk l (wave-contiguous 1 KB)
            A0 = *(const f16x8*)(w16 + tb + (size_t)l * 8);
            A1 = *(const f16x8*)(w16 + tb + 512 + (size_t)l * 8);
            if (!rv) {
                A0 = (f16x8){0, 0, 0, 0, 0, 0, 0, 0};
                A1 = A0;
            }
#pragma unroll
            for (int j = 0; j < 8; ++j) {
                wold[0][j] = (float)A0[j];
                wold[1][j] = (float)A1[j];
            }
        }
        // GEMM(i): z pre-adds
        floatx4 acc[4];
#pragma unroll
        for (int nt = 0; nt < 4; ++nt) {
            f16x8 B0 = *(const f16x8*)&Et1[(nt * 16 + r16) * ETS + q * 8];
            f16x8 B1 = *(const f16x8*)&Et1[(nt * 16 + r16) * ETS + 32 + q * 8];
            acc[nt] = (floatx4){0, 0, 0, 0};
            acc[nt] = __builtin_amdgcn_mfma_f32_16x16x32_f16(A0, B0, acc[nt], 0, 0, 0);
            acc[nt] = __builtin_amdgcn_mfma_f32_16x16x32_f16(A1, B1, acc[nt], 0, 0, 0);
        }
        // C -> A transform through wave-private LDS
#pragma unroll
        for (int rr = 0; rr < 4; ++rr) {
            int zr = q * 4 + rr;
#pragma unroll
            for (int nt = 0; nt < 4; ++nt) zb[zr * ZS + nt * 16 + r16] = acc[nt][rr];
        }
        float zA[2][8];
        *(float4*)&zA[0][0] = *(const float4*)&zb[r16 * ZS + q * 8];
        *(float4*)&zA[0][4] = *(const float4*)&zb[r16 * ZS + q * 8 + 4];
        *(float4*)&zA[1][0] = *(const float4*)&zb[r16 * ZS + 32 + q * 8];
        *(float4*)&zA[1][4] = *(const float4*)&zb[r16 * ZS + 32 + q * 8 + 4];
        // BN apply + residual (A layout)
        float x4v[2][8] = {{0, 0, 0, 0, 0, 0, 0, 0}, {0, 0, 0, 0, 0, 0, 0, 0}};
        if (rv) {
            const float* x4r = x4a + (size_t)(b * Nn + dst) * Uu;
            *(float4*)&x4v[0][0] = *(const float4*)(x4r + q * 8);
            *(float4*)&x4v[0][4] = *(const float4*)(x4r + q * 8 + 4);
            *(float4*)&x4v[1][0] = *(const float4*)(x4r + 32 + q * 8);
            *(float4*)&x4v[1][4] = *(const float4*)(x4r + 32 + q * 8 + 4);
        }
        float wnewf[2][8];
        f16x8 W0, W1;
#pragma unroll
        for (int g2 = 0; g2 < 2; ++g2)
#pragma unroll
            for (int j = 0; j < 8; ++j) {
                float z = zA[g2][j] + c1r[g2][j] + x4v[g2][j];
                wnewf[g2][j] = wold[g2][j] + lrelu(fmaf(z, ssc[g2][j], ssh[g2][j]));
            }
#pragma unroll
        for (int j = 0; j < 8; ++j) {
            W0[j] = (f16)wnewf[0][j];
            W1[j] = (f16)wnewf[1][j];
        }
        // tile-layout store: unconditional, wave-contiguous 1 KB per instruction
        *(f16x8*)(w16 + tb + (size_t)l * 8) = W0;
        *(f16x8*)(w16 + tb + 512 + (size_t)l * 8) = W1;
        if (POOL2 && rv) {
            const float* x2r = x2b + (size_t)(b * Nn + dst) * Uu;
#pragma unroll
            for (int g2 = 0; g2 < 2; ++g2) {
                float xv[8];
                *(float4*)&xv[0] = *(const float4*)(x2r + g2 * 32 + q * 8);
                *(float4*)&xv[4] = *(const float4*)(x2r + g2 * 32 + q * 8 + 4);
#pragma unroll
                for (int j = 0; j < 8; ++j)
                    pm[g2][j] = fmaxf(pm[g2][j], sigm(wnewf[g2][j]) * xv[j]);
            }
        }
        // GEMM(i+1) for stats
        floatx4 acc2[4];
#pragma unroll
        for (int nt = 0; nt < 4; ++nt) {
            f16x8 B0 = *(const f16x8*)&Et2[(nt * 16 + r16) * ETS + q * 8];
            f16x8 B1 = *(const f16x8*)&Et2[(nt * 16 + r16) * ETS + 32 + q * 8];
            acc2[nt] = (floatx4){0, 0, 0, 0};
            acc2[nt] = __builtin_amdgcn_mfma_f32_16x16x32_f16(W0, B0, acc2[nt], 0, 0, 0);
            acc2[nt] = __builtin_amdgcn_mfma_f32_16x16x32_f16(W1, B1, acc2[nt], 0, 0, 0);
        }
#pragma unroll
        for (int rr = 0; rr < 4; ++rr) {
            int k = mt * 16 + q * 4 + rr;
            if (k < NM1) {
                int d2 = dstcol(n, k);
                const float* x4r = x4b + (size_t)(b * Nn + d2) * Uu;
#pragma unroll
                for (int nt = 0; nt < 4; ++nt) {
                    int u = nt * 16 + r16;
                    float z = acc2[nt][rr] + c2s[u] + x4r[u];
                    sum[nt] += z;
                    sq[nt] = fmaf(z, z, sq[nt]);
                }
            }
        }
    }
#pragma unroll
    for (int nt = 0; nt < 4; ++nt) {
        sum[nt] += __shfl_xor(sum[nt], 16, 64);
        sum[nt] += __shfl_xor(sum[nt], 32, 64);
        sq[nt] += __shfl_xor(sq[nt], 16, 64);
        sq[nt] += __shfl_xor(sq[nt], 32, 64);
    }
    if (l < 16) {
#pragma unroll
        for (int nt = 0; nt < 4; ++nt) {
            atomicAdd(&sred[nt * 16 + l], sum[nt]);
            atomicAdd(&sred[64 + nt * 16 + l], sq[nt]);
        }
    }
    if (POOL2) {
#pragma unroll
        for (int g2 = 0; g2 < 2; ++g2)
#pragma unroll
            for (int j = 0; j < 8; ++j) {
                float v = pm[g2][j];
                v = fmaxf(v, __shfl_xor(v, 1, 64));
                v = fmaxf(v, __shfl_xor(v, 2, 64));
                v = fmaxf(v, __shfl_xor(v, 4, 64));
                v = fmaxf(v, __shfl_xor(v, 8, 64));
                pm[g2][j] = v;
            }
        if (r16 == 0) {
#pragma unroll
            for (int g2 = 0; g2 < 2; ++g2)
#pragma unroll
                for (int j = 0; j < 8; ++j) pbuf[wv][g2 * 32 + q * 8 + j] = pm[g2][j];
        }
    }
    __syncthreads();
    if (tid < 128) atomicAdd(&spread[(bn & (SPREAD - 1)) * 128 + tid], sred[tid]);
    if (POOL2 && tid < Uu)
        pooled[(size_t)bn * Uu + tid] =
            fmaxf(fmaxf(pbuf[0][tid], pbuf[1][tid]), fmaxf(pbuf[2][tid], pbuf[3][tid]));
}

// last: apply BN(2)+residual, dot with e_lin1, scatter to out
__global__ __launch_bounds__(256, 3) void k_last(
    const f16* __restrict__ w16, const float* __restrict__ ew1,
    const float* __restrict__ eb1, const float* __restrict__ x3a,
    const float* __restrict__ x4a, const float* __restrict__ wss,
    const float* __restrict__ elw, const float* __restrict__ elb,
    float* __restrict__ out) {
    __shared__ __align__(16) f16 Et1[Uu * ETS];
    __shared__ __align__(16) float zbuf[4][16 * ZS];
    __shared__ float c1s[Uu];
    int bn = blockIdx.x;
    int b = bn / Nn, n = bn % Nn;
    int tid = threadIdx.x;
    int l = tid & 63, wv = tid >> 6;
    int r16 = l & 15, q = l >> 4;
    stageEt(ew1, Et1, tid);
    if (tid < Uu) c1s[tid] = eb1[tid] + x3a[(size_t)bn * Uu + tid];
    __syncthreads();

    float ssc[2][8], ssh[2][8], c1r[2][8], elr[2][8];
#pragma unroll
    for (int g2 = 0; g2 < 2; ++g2)
#pragma unroll
        for (int j = 0; j < 8; ++j) {
            int ch = g2 * 32 + q * 8 + j;
            ssc[g2][j] = wss[ch];
            ssh[g2][j] = wss[64 + ch];
            c1r[g2][j] = c1s[ch];
            elr[g2][j] = elw[ch];
        }
    float elb0 = elb[0];
    f16x8 Bf[2][4];
#pragma unroll
    for (int hh = 0; hh < 2; ++hh)
#pragma unroll
        for (int nt = 0; nt < 4; ++nt)
            Bf[hh][nt] = *(const f16x8*)&Et1[(nt * 16 + r16) * ETS + hh * 32 + q * 8];
    float* zb = zbuf[wv];

    for (int mt = wv; mt < 13; mt += 4) {
        int row = mt * 16 + r16;
        bool rv = row < NM1;
        int dst = dstcol(n, rv ? row : 0);
        size_t tb = tbase(bn, mt);
        f16x8 A0 = *(const f16x8*)(w16 + tb + (size_t)l * 8);
        f16x8 A1 = *(const f16x8*)(w16 + tb + 512 + (size_t)l * 8);
        if (!rv) {
            A0 = (f16x8){0, 0, 0, 0, 0, 0, 0, 0};
            A1 = A0;
        }
        float wold[2][8];
#pragma unroll
        for (int j = 0; j < 8; ++j) {
            wold[0][j] = (float)A0[j];
            wold[1][j] = (float)A1[j];
        }
        floatx4 acc[4];
#pragma unroll
        for (int nt = 0; nt < 4; ++nt) {
            acc[nt] = (floatx4){0, 0, 0, 0};
            acc[nt] = __builtin_amdgcn_mfma_f32_16x16x32_f16(A0, Bf[0][nt], acc[nt], 0, 0, 0);
            acc[nt] = __builtin_amdgcn_mfma_f32_16x16x32_f16(A1, Bf[1][nt], acc[nt], 0, 0, 0);
        }
#pragma unroll
        for (int rr = 0; rr < 4; ++rr) {
            int zr = q * 4 + rr;
#pragma unroll
            for (int nt = 0; nt < 4; ++nt) zb[zr * ZS + nt * 16 + r16] = acc[nt][rr];
        }
        float zA[2][8];
        *(float4*)&zA[0][0] = *(const float4*)&zb[r16 * ZS + q * 8];
        *(float4*)&zA[0][4] = *(const float4*)&zb[r16 * ZS + q * 8 + 4];
        *(float4*)&zA[1][0] = *(const float4*)&zb[r16 * ZS + 32 + q * 8];
        *(float4*)&zA[1][4] = *(const float4*)&zb[r16 * ZS + 32 + q * 8 + 4];
        float x4v[2][8] = {{0, 0, 0, 0, 0, 0, 0, 0}, {0, 0, 0, 0, 0, 0, 0, 0}};
        if (rv) {
            const float* x4r = x4a + (size_t)(b * Nn + dst) * Uu;
            *(float4*)&x4v[0][0] = *(const float4*)(x4r + q * 8);
            *(float4*)&x4v[0][4] = *(const float4*)(x4r + q * 8 + 4);
            *(float4*)&x4v[1][0] = *(const float4*)(x4r + 32 + q * 8);
            *(float4*)&x4v[1][4] = *(const float4*)(x4r + 32 + q * 8 + 4);
        }
        float t = 0.f;
#pragma unroll
        for (int g2 = 0; g2 < 2; ++g2)
#pragma unroll
            for (int j = 0; j < 8; ++j) {
                float z = zA[g2][j] + c1r[g2][j] + x4v[g2][j];
                float wn = wold[g2][j] + lrelu(fmaf(z, ssc[g2][j], ssh[g2][j]));
                t = fmaf(wn, elr[g2][j], t);
            }
        t += __shfl_xor(t, 16, 64);
        t += __shfl_xor(t, 32, 64);
        if (q == 0 && rv) out[(size_t)bn * Nn + dst] = t + elb0;
    }
    if (tid == 0) out[(size_t)bn * Nn + n] = 0.f;
}

// finw (block 64) + hup (blocks 0..63)
__global__ void k_mid(const float* __restrict__ spread, const float* __restrict__ eg,
                      const float* __restrict__ ebb, float* __restrict__ wss,
                      const float* __restrict__ x1, const float* __restrict__ pooled,
                      const float* __restrict__ vg, const float* __restrict__ vbb,
                      float* __restrict__ h) {
    if (blockIdx.x == 64) {
        int u = threadIdx.x;
        if (u < 64) {
            float s = 0.f, sqv = 0.f;
            for (int p = 0; p < SPREAD; ++p) {
                s += spread[p * 128 + u];
                sqv += spread[p * 128 + 64 + u];
            }
            const float Mf = (float)((size_t)Bb * Nn * NM1);
            float mean = s / Mf;
            float var = fmaxf(sqv / Mf - mean * mean, 0.f);
            float inv = rsqrtf(var + EPSBN);
            float scale = eg[u] * inv;
            wss[u] = scale;
            wss[64 + u] = ebb[u] - mean * scale;
        }
        return;
    }
    __shared__ float red[256], red2[256];
    int ch = blockIdx.x;
    int t = threadIdx.x;
    float s = 0.f, sqv = 0.f;
    for (int bn = t; bn < Bb * Nn; bn += 256) {
        float v = x1[bn * Uu + ch] + pooled[bn * Uu + ch];
        s += v;
        sqv = fmaf(v, v, sqv);
    }
    red[t] = s;
    red2[t] = sqv;
    __syncthreads();
    for (int off = 128; off; off >>= 1) {
        if (t < off) {
            red[t] += red[t + off];
            red2[t] += red2[t + off];
        }
        __syncthreads();
    }
    const float Mf = (float)(Bb * Nn);
    float mean = red[0] / Mf;
    float var = fmaxf(red2[0] / Mf - mean * mean, 0.f);
    float inv = rsqrtf(var + EPSBN);
    float scale = vg[ch] * inv;
    float shift = vbb[ch] - mean * scale;
    for (int bn = t; bn < Bb * Nn; bn += 256) {
        float v = x1[bn * Uu + ch] + pooled[bn * Uu + ch];
        h[bn * Uu + ch] += lrelu(fmaf(v, scale, shift));
    }
}

__global__ void k_finw(const float* __restrict__ spread, const float* __restrict__ g,
                       const float* __restrict__ bb, float* __restrict__ wss) {
    int u = threadIdx.x;
    float s = 0.f, sq = 0.f;
    for (int p = 0; p < SPREAD; ++p) {
        s += spread[p * 128 + u];
        sq += spread[p * 128 + 64 + u];
    }
    const float Mf = (float)((size_t)Bb * Nn * NM1);
    float mean = s / Mf;
    float var = fmaxf(sq / Mf - mean * mean, 0.f);
    float inv = rsqrtf(var + EPSBN);
    float scale = g[u] * inv;
    wss[u] = scale;
    wss[64 + u] = bb[u] - mean * scale;
}

extern "C" void kernel_launch(void* const* d_in, const int* in_sizes, int n_in,
                              void* d_out, int out_size, void* d_ws, size_t ws_size,
                              hipStream_t stream) {
    const float* x = (const float*)d_in[0];
    const float* adj = (const float*)d_in[1];
    const float* vl0w = (const float*)d_in[2];
    const float* vl0b = (const float*)d_in[3];
    const float* vw1 = (const float*)d_in[4];
    const float* vb1 = (const float*)d_in[5];
    const float* vw2 = (const float*)d_in[6];
    const float* vb2 = (const float*)d_in[7];
    const float* vw3 = (const float*)d_in[8];
    const float* vb3 = (const float*)d_in[9];
    const float* vw4 = (const float*)d_in[10];
    const float* vb4 = (const float*)d_in[11];
    const float* vbng = (const float*)d_in[12];
    const float* vbnb = (const float*)d_in[13];
    const float* e0w = (const float*)d_in[14];
    const float* e0b = (const float*)d_in[15];
    const float* ew = (const float*)d_in[16];
    const float* eb = (const float*)d_in[17];
    const float* ebng = (const float*)d_in[18];
    const float* ebnb = (const float*)d_in[19];
    const float* elw = (const float*)d_in[20];
    const float* elb = (const float*)d_in[21];
    float* out = (float*)d_out;

    f16* w16 = (f16*)d_ws;                      // 3200*13*1024 = 42,598,400 f16
    float* fb = (float*)d_ws + 21299200;
    const size_t NV = 204800;
    float* h = fb;
    float* xv1[3] = {fb + NV, fb + 2 * NV, fb + 3 * NV};
    float* xv2[3] = {fb + 4 * NV, fb + 5 * NV, fb + 6 * NV};
    float* xv3[3] = {fb + 7 * NV, fb + 8 * NV, fb + 9 * NV};
    float* xv4[3] = {fb + 10 * NV, fb + 11 * NV, fb + 12 * NV};
    float* pooled = fb + 13 * NV;
    float* spread = fb + 14 * NV;               // SPREAD*128
    float* wss = spread + SPREAD * 128;         // 128

    const int GRID = Bb * Nn;  // 3200

    k_xvec<true><<<GRID, 64, 0, stream>>>(x, vl0w, vl0b, h, vw1, vb1, vw2, vb2, vw3,
                                          vb3, vw4, vb4, xv1[0], xv2[0], xv3[0],
                                          xv4[0], spread);
    k_first<<<GRID, 256, 0, stream>>>(adj, ew, eb, e0w, e0b, xv2[0], xv3[0], xv4[0],
                                      pooled, spread);
    k_mid<<<65, 256, 0, stream>>>(spread, ebng, ebnb, wss, xv1[0], pooled, vbng,
                                  vbnb, h);
    k_xvec<false><<<GRID, 64, 0, stream>>>(x, vl0w, vl0b, h, vw1 + 4096, vb1 + 64,
                                           vw2 + 4096, vb2 + 64, vw3 + 4096, vb3 + 64,
                                           vw4 + 4096, vb4 + 64, xv1[1], xv2[1],
                                           xv3[1], xv4[1], spread);
    k_fused<true, true><<<GRID, 256, 0, stream>>>(
        adj, w16, ew, eb, ew + 4096, eb + 64, e0w, e0b, xv3[0], xv4[0], xv2[1],
        xv3[1], xv4[1], wss, pooled, spread);
    k_mid<<<65, 256, 0, stream>>>(spread, ebng + 64, ebnb + 64, wss, xv1[1], pooled,
                                  vbng + 64, vbnb + 64, h);
    k_xvec<false><<<GRID, 64, 0, stream>>>(x, vl0w, vl0b, h, vw1 + 8192, vb1 + 128,
                                           vw2 + 8192, vb2 + 128, vw3 + 8192,
                                           vb3 + 128, vw4 + 8192, vb4 + 128, xv1[2],
                                           xv2[2], xv3[2], xv4[2], spread);
    k_fused<false, false><<<GRID, 256, 0, stream>>>(
        adj, w16, ew + 4096, eb + 64, ew + 8192, eb + 128, e0w, e0b, xv3[1], xv4[1],
        xv2[2], xv3[2], xv4[2], wss, pooled, spread);
    k_finw<<<1, 64, 0, stream>>>(spread, ebng + 128, ebnb + 128, wss);
    k_last<<<GRID, 256, 0, stream>>>(w16, ew + 8192, eb + 128, xv3[2], xv4[2], wss,
                                     elw, elb, out);
}

// Round 5
// 577.460 us; speedup vs baseline: 1.1193x; 1.0931x over previous
//
#include <hip/hip_runtime.h>

#define Bb 16
#define Nn 200
#define NM1 199
#define Uu 64
#define EPSBN 1e-5f
#define SLOPE 0.01f
#define SPREAD 64
#define ETS 72   // f16 elems per Et row (64 + 8 pad)
#define ZS 68    // f32 elems per zbuf row (64 + 4 pad, keeps 16B alignment)

typedef _Float16 f16;
typedef __attribute__((ext_vector_type(8))) _Float16 f16x8;
typedef __attribute__((ext_vector_type(2))) _Float16 f16x2;
typedef __attribute__((ext_vector_type(4))) float floatx4;

// w16 tile layout: per (bn, mt) a 1024-f16 tile; chunk l (16 B) == lane l's
// A-fragment (KB0 at +0, KB1 at +512 elems). Wave-contiguous 1 KB per access.
__device__ __forceinline__ size_t tbase(int bn, int mt) {
    return ((size_t)bn * 13 + mt) * 1024;
}

__device__ __forceinline__ float lrelu(float v) { return v > 0.f ? v : SLOPE * v; }
__device__ __forceinline__ int dstcol(int n, int k) { return k < n ? k : k + 1; }
__device__ __forceinline__ float sigm(float v) { return 1.f / (1.f + __expf(-v)); }

__device__ __forceinline__ f16x8 ntload8(const f16* p) {
    return __builtin_nontemporal_load((const f16x8*)p);
}
__device__ __forceinline__ void ntstore8(f16* p, f16x8 v) {
    __builtin_nontemporal_store(v, (f16x8*)p);
}

__device__ __forceinline__ void stageEt(const float* __restrict__ ew, f16* Et, int tid) {
    int u = tid & 63, g = tid >> 6;
#pragma unroll
    for (int pp = 0; pp < 8; ++pp) {
        int jp = g + pp * 4;
        f16x2 pk;
        pk.x = (f16)ew[(2 * jp) * Uu + u];
        pk.y = (f16)ew[(2 * jp + 1) * Uu + u];
        *(f16x2*)&Et[u * ETS + 2 * jp] = pk;
    }
}

// x-vec projections; L0 also computes h from x; block 0 zeroes spread
template <bool L0>
__global__ void k_xvec(const float* __restrict__ xin, const float* __restrict__ l0w,
                       const float* __restrict__ l0b, float* __restrict__ h,
                       const float* __restrict__ w1, const float* __restrict__ b1,
                       const float* __restrict__ w2, const float* __restrict__ b2,
                       const float* __restrict__ w3, const float* __restrict__ b3,
                       const float* __restrict__ w4, const float* __restrict__ b4,
                       float* __restrict__ x1, float* __restrict__ x2,
                       float* __restrict__ x3, float* __restrict__ x4,
                       float* __restrict__ spread) {
    __shared__ float hrow[Uu];
    int bn = blockIdx.x;
    int u = threadIdx.x;
    if (blockIdx.x == 0) {
        for (int t = u; t < SPREAD * 128; t += Uu) spread[t] = 0.f;
    }
    if (L0) {
        float v = fmaf(xin[bn * 2], l0w[u], fmaf(xin[bn * 2 + 1], l0w[Uu + u], l0b[u]));
        v = lrelu(v);
        hrow[u] = v;
        h[bn * Uu + u] = v;
    } else {
        hrow[u] = h[bn * Uu + u];
    }
    __syncthreads();
    float a1 = b1[u], a2 = b2[u], a3 = b3[u], a4 = b4[u];
#pragma unroll 8
    for (int j = 0; j < Uu; ++j) {
        float hv = hrow[j];
        a1 = fmaf(hv, w1[j * Uu + u], a1);
        a2 = fmaf(hv, w2[j * Uu + u], a2);
        a3 = fmaf(hv, w3[j * Uu + u], a3);
        a4 = fmaf(hv, w4[j * Uu + u], a4);
    }
    x1[bn * Uu + u] = a1;
    x2[bn * Uu + u] = a2;
    x3[bn * Uu + u] = a3;
    x4[bn * Uu + u] = a4;
}

// layer-0 stats + pooled; w0 recomputed from adj, never stored
__global__ __launch_bounds__(256, 3) void k_first(
    const float* __restrict__ adj,
    const float* __restrict__ ew1, const float* __restrict__ eb1,
    const float* __restrict__ e0w, const float* __restrict__ e0b,
    const float* __restrict__ x2a, const float* __restrict__ x3a,
    const float* __restrict__ x4a,
    float* __restrict__ pooled, float* __restrict__ spread) {
    __shared__ __align__(16) f16 Et[Uu * ETS];
    __shared__ float c2s[Uu];
    __shared__ float sred[128];
    __shared__ float pbuf[4][Uu];
    int bn = blockIdx.x;
    int b = bn / Nn, n = bn % Nn;
    int tid = threadIdx.x;
    int l = tid & 63, wv = tid >> 6;
    int r16 = l & 15, q = l >> 4;
    stageEt(ew1, Et, tid);
    if (tid < Uu) c2s[tid] = eb1[tid] + x3a[(size_t)bn * Uu + tid];
    if (tid < 128) sred[tid] = 0.f;
    __syncthreads();

    float e0r[2][8], e0br[2][8];
#pragma unroll
    for (int g2 = 0; g2 < 2; ++g2)
#pragma unroll
        for (int j = 0; j < 8; ++j) {
            int ch = g2 * 32 + q * 8 + j;
            e0r[g2][j] = e0w[ch];
            e0br[g2][j] = e0b[ch];
        }

    const float* adjrow = adj + (size_t)bn * Nn;
    float sum[4] = {0, 0, 0, 0}, sq[4] = {0, 0, 0, 0};
    float pm[2][8];
#pragma unroll
    for (int g2 = 0; g2 < 2; ++g2)
#pragma unroll
        for (int j = 0; j < 8; ++j) pm[g2][j] = -3.402823e38f;

    for (int mt = wv; mt < 13; mt += 4) {
        int row = mt * 16 + r16;
        bool rv = row < NM1;
        int dst = dstcol(n, rv ? row : 0);
        float adv = rv ? adjrow[dst] : 0.f;
        float w0[2][8];
        f16x8 A0, A1;
#pragma unroll
        for (int j = 0; j < 8; ++j) {
            w0[0][j] = lrelu(fmaf(adv, e0r[0][j], e0br[0][j]));
            w0[1][j] = lrelu(fmaf(adv, e0r[1][j], e0br[1][j]));
            A0[j] = (f16)w0[0][j];
            A1[j] = (f16)w0[1][j];
        }
        if (!rv) {
            A0 = (f16x8){0, 0, 0, 0, 0, 0, 0, 0};
            A1 = A0;
        }
        floatx4 acc[4];
#pragma unroll
        for (int nt = 0; nt < 4; ++nt) {
            f16x8 B0 = *(const f16x8*)&Et[(nt * 16 + r16) * ETS + q * 8];
            f16x8 B1 = *(const f16x8*)&Et[(nt * 16 + r16) * ETS + 32 + q * 8];
            acc[nt] = (floatx4){0, 0, 0, 0};
            acc[nt] = __builtin_amdgcn_mfma_f32_16x16x32_f16(A0, B0, acc[nt], 0, 0, 0);
            acc[nt] = __builtin_amdgcn_mfma_f32_16x16x32_f16(A1, B1, acc[nt], 0, 0, 0);
        }
#pragma unroll
        for (int rr = 0; rr < 4; ++rr) {
            int k = mt * 16 + q * 4 + rr;
            if (k < NM1) {
                int d2 = dstcol(n, k);
                const float* x4r = x4a + (size_t)(b * Nn + d2) * Uu;
#pragma unroll
                for (int nt = 0; nt < 4; ++nt) {
                    int u = nt * 16 + r16;
                    float z = acc[nt][rr] + c2s[u] + x4r[u];
                    sum[nt] += z;
                    sq[nt] = fmaf(z, z, sq[nt]);
                }
            }
        }
        if (rv) {
            const float* x2r = x2a + (size_t)(b * Nn + dst) * Uu;
#pragma unroll
            for (int g2 = 0; g2 < 2; ++g2) {
                float xv[8];
                *(float4*)&xv[0] = *(const float4*)(x2r + g2 * 32 + q * 8);
                *(float4*)&xv[4] = *(const float4*)(x2r + g2 * 32 + q * 8 + 4);
#pragma unroll
                for (int j = 0; j < 8; ++j)
                    pm[g2][j] = fmaxf(pm[g2][j], sigm(w0[g2][j]) * xv[j]);
            }
        }
    }
#pragma unroll
    for (int nt = 0; nt < 4; ++nt) {
        sum[nt] += __shfl_xor(sum[nt], 16, 64);
        sum[nt] += __shfl_xor(sum[nt], 32, 64);
        sq[nt] += __shfl_xor(sq[nt], 16, 64);
        sq[nt] += __shfl_xor(sq[nt], 32, 64);
    }
    if (l < 16) {
#pragma unroll
        for (int nt = 0; nt < 4; ++nt) {
            atomicAdd(&sred[nt * 16 + l], sum[nt]);
            atomicAdd(&sred[64 + nt * 16 + l], sq[nt]);
        }
    }
#pragma unroll
    for (int g2 = 0; g2 < 2; ++g2)
#pragma unroll
        for (int j = 0; j < 8; ++j) {
            float v = pm[g2][j];
            v = fmaxf(v, __shfl_xor(v, 1, 64));
            v = fmaxf(v, __shfl_xor(v, 2, 64));
            v = fmaxf(v, __shfl_xor(v, 4, 64));
            v = fmaxf(v, __shfl_xor(v, 8, 64));
            pm[g2][j] = v;
        }
    if (r16 == 0) {
#pragma unroll
        for (int g2 = 0; g2 < 2; ++g2)
#pragma unroll
            for (int j = 0; j < 8; ++j) pbuf[wv][g2 * 32 + q * 8 + j] = pm[g2][j];
    }
    __syncthreads();
    if (tid < 128) atomicAdd(&spread[(bn & (SPREAD - 1)) * 128 + tid], sred[tid]);
    if (tid < Uu)
        pooled[(size_t)bn * Uu + tid] =
            fmaxf(fmaxf(pbuf[0][tid], pbuf[1][tid]), fmaxf(pbuf[2][tid], pbuf[3][tid]));
}

// apply BN(i)+residual -> wnew (NT tile store) + pool(i+1)
template <bool FIRST>
__global__ __launch_bounds__(256, 3) void k_apply(
    const float* __restrict__ adj, f16* __restrict__ w16,
    const float* __restrict__ ew1, const float* __restrict__ eb1,
    const float* __restrict__ e0w, const float* __restrict__ e0b,
    const float* __restrict__ x3a, const float* __restrict__ x4a,
    const float* __restrict__ x2b, const float* __restrict__ wss,
    float* __restrict__ pooled) {
    __shared__ __align__(16) f16 Et1[Uu * ETS];
    __shared__ __align__(16) float zbuf[4][16 * ZS];
    __shared__ float c1s[Uu];
    __shared__ float pbuf[4][Uu];
    int bn = blockIdx.x;
    int b = bn / Nn, n = bn % Nn;
    int tid = threadIdx.x;
    int l = tid & 63, wv = tid >> 6;
    int r16 = l & 15, q = l >> 4;
    stageEt(ew1, Et1, tid);
    if (tid < Uu) c1s[tid] = eb1[tid] + x3a[(size_t)bn * Uu + tid];
    __syncthreads();

    float ssc[2][8], ssh[2][8], c1r[2][8];
    float e0r[2][8], e0br[2][8];
#pragma unroll
    for (int g2 = 0; g2 < 2; ++g2)
#pragma unroll
        for (int j = 0; j < 8; ++j) {
            int ch = g2 * 32 + q * 8 + j;
            ssc[g2][j] = wss[ch];
            ssh[g2][j] = wss[64 + ch];
            c1r[g2][j] = c1s[ch];
            if (FIRST) {
                e0r[g2][j] = e0w[ch];
                e0br[g2][j] = e0b[ch];
            }
        }

    const float* adjrow = adj + (size_t)bn * Nn;
    float pm[2][8];
#pragma unroll
    for (int g2 = 0; g2 < 2; ++g2)
#pragma unroll
        for (int j = 0; j < 8; ++j) pm[g2][j] = -3.402823e38f;
    float* zb = zbuf[wv];

    for (int mt = wv; mt < 13; mt += 4) {
        int row = mt * 16 + r16;
        bool rv = row < NM1;
        int dst = dstcol(n, rv ? row : 0);
        size_t tb = tbase(bn, mt);
        f16x8 A0, A1;
        float wold[2][8];
        if (FIRST) {
            float adv = rv ? adjrow[dst] : 0.f;
#pragma unroll
            for (int j = 0; j < 8; ++j) {
                wold[0][j] = lrelu(fmaf(adv, e0r[0][j], e0br[0][j]));
                wold[1][j] = lrelu(fmaf(adv, e0r[1][j], e0br[1][j]));
                A0[j] = (f16)wold[0][j];
                A1[j] = (f16)wold[1][j];
            }
            if (!rv) {
                A0 = (f16x8){0, 0, 0, 0, 0, 0, 0, 0};
                A1 = A0;
            }
        } else {
            A0 = ntload8(w16 + tb + (size_t)l * 8);
            A1 = ntload8(w16 + tb + 512 + (size_t)l * 8);
            if (!rv) {
                A0 = (f16x8){0, 0, 0, 0, 0, 0, 0, 0};
                A1 = A0;
            }
#pragma unroll
            for (int j = 0; j < 8; ++j) {
                wold[0][j] = (float)A0[j];
                wold[1][j] = (float)A1[j];
            }
        }
        floatx4 acc[4];
#pragma unroll
        for (int nt = 0; nt < 4; ++nt) {
            f16x8 B0 = *(const f16x8*)&Et1[(nt * 16 + r16) * ETS + q * 8];
            f16x8 B1 = *(const f16x8*)&Et1[(nt * 16 + r16) * ETS + 32 + q * 8];
            acc[nt] = (floatx4){0, 0, 0, 0};
            acc[nt] = __builtin_amdgcn_mfma_f32_16x16x32_f16(A0, B0, acc[nt], 0, 0, 0);
            acc[nt] = __builtin_amdgcn_mfma_f32_16x16x32_f16(A1, B1, acc[nt], 0, 0, 0);
        }
        // C -> A transform through wave-private LDS
#pragma unroll
        for (int rr = 0; rr < 4; ++rr) {
            int zr = q * 4 + rr;
#pragma unroll
            for (int nt = 0; nt < 4; ++nt) zb[zr * ZS + nt * 16 + r16] = acc[nt][rr];
        }
        float zA[2][8];
        *(float4*)&zA[0][0] = *(const float4*)&zb[r16 * ZS + q * 8];
        *(float4*)&zA[0][4] = *(const float4*)&zb[r16 * ZS + q * 8 + 4];
        *(float4*)&zA[1][0] = *(const float4*)&zb[r16 * ZS + 32 + q * 8];
        *(float4*)&zA[1][4] = *(const float4*)&zb[r16 * ZS + 32 + q * 8 + 4];
        float x4v[2][8] = {{0, 0, 0, 0, 0, 0, 0, 0}, {0, 0, 0, 0, 0, 0, 0, 0}};
        if (rv) {
            const float* x4r = x4a + (size_t)(b * Nn + dst) * Uu;
            *(float4*)&x4v[0][0] = *(const float4*)(x4r + q * 8);
            *(float4*)&x4v[0][4] = *(const float4*)(x4r + q * 8 + 4);
            *(float4*)&x4v[1][0] = *(const float4*)(x4r + 32 + q * 8);
            *(float4*)&x4v[1][4] = *(const float4*)(x4r + 32 + q * 8 + 4);
        }
        float wnewf[2][8];
        f16x8 W0, W1;
#pragma unroll
        for (int g2 = 0; g2 < 2; ++g2)
#pragma unroll
            for (int j = 0; j < 8; ++j) {
                float z = zA[g2][j] + c1r[g2][j] + x4v[g2][j];
                wnewf[g2][j] = wold[g2][j] + lrelu(fmaf(z, ssc[g2][j], ssh[g2][j]));
            }
#pragma unroll
        for (int j = 0; j < 8; ++j) {
            W0[j] = (f16)wnewf[0][j];
            W1[j] = (f16)wnewf[1][j];
        }
        ntstore8(w16 + tb + (size_t)l * 8, W0);
        ntstore8(w16 + tb + 512 + (size_t)l * 8, W1);
        if (rv) {
            const float* x2r = x2b + (size_t)(b * Nn + dst) * Uu;
#pragma unroll
            for (int g2 = 0; g2 < 2; ++g2) {
                float xv[8];
                *(float4*)&xv[0] = *(const float4*)(x2r + g2 * 32 + q * 8);
                *(float4*)&xv[4] = *(const float4*)(x2r + g2 * 32 + q * 8 + 4);
#pragma unroll
                for (int j = 0; j < 8; ++j)
                    pm[g2][j] = fmaxf(pm[g2][j], sigm(wnewf[g2][j]) * xv[j]);
            }
        }
    }
#pragma unroll
    for (int g2 = 0; g2 < 2; ++g2)
#pragma unroll
        for (int j = 0; j < 8; ++j) {
            float v = pm[g2][j];
            v = fmaxf(v, __shfl_xor(v, 1, 64));
            v = fmaxf(v, __shfl_xor(v, 2, 64));
            v = fmaxf(v, __shfl_xor(v, 4, 64));
            v = fmaxf(v, __shfl_xor(v, 8, 64));
            pm[g2][j] = v;
        }
    if (r16 == 0) {
#pragma unroll
        for (int g2 = 0; g2 < 2; ++g2)
#pragma unroll
            for (int j = 0; j < 8; ++j) pbuf[wv][g2 * 32 + q * 8 + j] = pm[g2][j];
    }
    __syncthreads();
    if (tid < Uu)
        pooled[(size_t)bn * Uu + tid] =
            fmaxf(fmaxf(pbuf[0][tid], pbuf[1][tid]), fmaxf(pbuf[2][tid], pbuf[3][tid]));
}

// stats-only pass: NT-read w16, GEMM(Et), BN stats of z
__global__ __launch_bounds__(256, 4) void k_p1s(
    const f16* __restrict__ w16, const float* __restrict__ ew2,
    const float* __restrict__ eb2, const float* __restrict__ x3b,
    const float* __restrict__ x4b, float* __restrict__ spread) {
    __shared__ __align__(16) f16 Et[Uu * ETS];
    __shared__ float c2s[Uu];
    __shared__ float sred[128];
    int bn = blockIdx.x;
    int b = bn / Nn, n = bn % Nn;
    int tid = threadIdx.x;
    int l = tid & 63, wv = tid >> 6;
    int r16 = l & 15, q = l >> 4;
    stageEt(ew2, Et, tid);
    if (tid < Uu) c2s[tid] = eb2[tid] + x3b[(size_t)bn * Uu + tid];
    if (tid < 128) sred[tid] = 0.f;
    __syncthreads();

    float sum[4] = {0, 0, 0, 0}, sq[4] = {0, 0, 0, 0};

    for (int mt = wv; mt < 13; mt += 4) {
        int row = mt * 16 + r16;
        bool rv = row < NM1;
        size_t tb = tbase(bn, mt);
        f16x8 A0 = ntload8(w16 + tb + (size_t)l * 8);
        f16x8 A1 = ntload8(w16 + tb + 512 + (size_t)l * 8);
        if (!rv) {
            A0 = (f16x8){0, 0, 0, 0, 0, 0, 0, 0};
            A1 = A0;
        }
        floatx4 acc[4];
#pragma unroll
        for (int nt = 0; nt < 4; ++nt) {
            f16x8 B0 = *(const f16x8*)&Et[(nt * 16 + r16) * ETS + q * 8];
            f16x8 B1 = *(const f16x8*)&Et[(nt * 16 + r16) * ETS + 32 + q * 8];
            acc[nt] = (floatx4){0, 0, 0, 0};
            acc[nt] = __builtin_amdgcn_mfma_f32_16x16x32_f16(A0, B0, acc[nt], 0, 0, 0);
            acc[nt] = __builtin_amdgcn_mfma_f32_16x16x32_f16(A1, B1, acc[nt], 0, 0, 0);
        }
#pragma unroll
        for (int rr = 0; rr < 4; ++rr) {
            int k = mt * 16 + q * 4 + rr;
            if (k < NM1) {
                int d2 = dstcol(n, k);
                const float* x4r = x4b + (size_t)(b * Nn + d2) * Uu;
#pragma unroll
                for (int nt = 0; nt < 4; ++nt) {
                    int u = nt * 16 + r16;
                    float z = acc[nt][rr] + c2s[u] + x4r[u];
                    sum[nt] += z;
                    sq[nt] = fmaf(z, z, sq[nt]);
                }
            }
        }
    }
#pragma unroll
    for (int nt = 0; nt < 4; ++nt) {
        sum[nt] += __shfl_xor(sum[nt], 16, 64);
        sum[nt] += __shfl_xor(sum[nt], 32, 64);
        sq[nt] += __shfl_xor(sq[nt], 16, 64);
        sq[nt] += __shfl_xor(sq[nt], 32, 64);
    }
    if (l < 16) {
#pragma unroll
        for (int nt = 0; nt < 4; ++nt) {
            atomicAdd(&sred[nt * 16 + l], sum[nt]);
            atomicAdd(&sred[64 + nt * 16 + l], sq[nt]);
        }
    }
    __syncthreads();
    if (tid < 128) atomicAdd(&spread[(bn & (SPREAD - 1)) * 128 + tid], sred[tid]);
}

// last: apply BN(2)+residual, dot with e_lin1, scatter to out
__global__ __launch_bounds__(256, 3) void k_last(
    const f16* __restrict__ w16, const float* __restrict__ ew1,
    const float* __restrict__ eb1, const float* __restrict__ x3a,
    const float* __restrict__ x4a, const float* __restrict__ wss,
    const float* __restrict__ elw, const float* __restrict__ elb,
    float* __restrict__ out) {
    __shared__ __align__(16) f16 Et1[Uu * ETS];
    __shared__ __align__(16) float zbuf[4][16 * ZS];
    __shared__ float c1s[Uu];
    int bn = blockIdx.x;
    int b = bn / Nn, n = bn % Nn;
    int tid = threadIdx.x;
    int l = tid & 63, wv = tid >> 6;
    int r16 = l & 15, q = l >> 4;
    stageEt(ew1, Et1, tid);
    if (tid < Uu) c1s[tid] = eb1[tid] + x3a[(size_t)bn * Uu + tid];
    __syncthreads();

    float ssc[2][8], ssh[2][8], c1r[2][8], elr[2][8];
#pragma unroll
    for (int g2 = 0; g2 < 2; ++g2)
#pragma unroll
        for (int j = 0; j < 8; ++j) {
            int ch = g2 * 32 + q * 8 + j;
            ssc[g2][j] = wss[ch];
            ssh[g2][j] = wss[64 + ch];
            c1r[g2][j] = c1s[ch];
            elr[g2][j] = elw[ch];
        }
    float elb0 = elb[0];
    float* zb = zbuf[wv];

    for (int mt = wv; mt < 13; mt += 4) {
        int row = mt * 16 + r16;
        bool rv = row < NM1;
        int dst = dstcol(n, rv ? row : 0);
        size_t tb = tbase(bn, mt);
        f16x8 A0 = ntload8(w16 + tb + (size_t)l * 8);
        f16x8 A1 = ntload8(w16 + tb + 512 + (size_t)l * 8);
        if (!rv) {
            A0 = (f16x8){0, 0, 0, 0, 0, 0, 0, 0};
            A1 = A0;
        }
        float wold[2][8];
#pragma unroll
        for (int j = 0; j < 8; ++j) {
            wold[0][j] = (float)A0[j];
            wold[1][j] = (float)A1[j];
        }
        floatx4 acc[4];
#pragma unroll
        for (int nt = 0; nt < 4; ++nt) {
            f16x8 B0 = *(const f16x8*)&Et1[(nt * 16 + r16) * ETS + q * 8];
            f16x8 B1 = *(const f16x8*)&Et1[(nt * 16 + r16) * ETS + 32 + q * 8];
            acc[nt] = (floatx4){0, 0, 0, 0};
            acc[nt] = __builtin_amdgcn_mfma_f32_16x16x32_f16(A0, B0, acc[nt], 0, 0, 0);
            acc[nt] = __builtin_amdgcn_mfma_f32_16x16x32_f16(A1, B1, acc[nt], 0, 0, 0);
        }
#pragma unroll
        for (int rr = 0; rr < 4; ++rr) {
            int zr = q * 4 + rr;
#pragma unroll
            for (int nt = 0; nt < 4; ++nt) zb[zr * ZS + nt * 16 + r16] = acc[nt][rr];
        }
        float zA[2][8];
        *(float4*)&zA[0][0] = *(const float4*)&zb[r16 * ZS + q * 8];
        *(float4*)&zA[0][4] = *(const float4*)&zb[r16 * ZS + q * 8 + 4];
        *(float4*)&zA[1][0] = *(const float4*)&zb[r16 * ZS + 32 + q * 8];
        *(float4*)&zA[1][4] = *(const float4*)&zb[r16 * ZS + 32 + q * 8 + 4];
        float x4v[2][8] = {{0, 0, 0, 0, 0, 0, 0, 0}, {0, 0, 0, 0, 0, 0, 0, 0}};
        if (rv) {
            const float* x4r = x4a + (size_t)(b * Nn + dst) * Uu;
            *(float4*)&x4v[0][0] = *(const float4*)(x4r + q * 8);
            *(float4*)&x4v[0][4] = *(const float4*)(x4r + q * 8 + 4);
            *(float4*)&x4v[1][0] = *(const float4*)(x4r + 32 + q * 8);
            *(float4*)&x4v[1][4] = *(const float4*)(x4r + 32 + q * 8 + 4);
        }
        float t = 0.f;
#pragma unroll
        for (int g2 = 0; g2 < 2; ++g2)
#pragma unroll
            for (int j = 0; j < 8; ++j) {
                float z = zA[g2][j] + c1r[g2][j] + x4v[g2][j];
                float wn = wold[g2][j] + lrelu(fmaf(z, ssc[g2][j], ssh[g2][j]));
                t = fmaf(wn, elr[g2][j], t);
            }
        t += __shfl_xor(t, 16, 64);
        t += __shfl_xor(t, 32, 64);
        if (q == 0 && rv) out[(size_t)bn * Nn + dst] = t + elb0;
    }
    if (tid == 0) out[(size_t)bn * Nn + n] = 0.f;
}

// finw (block 64) + hup (blocks 0..63)
__global__ void k_mid(const float* __restrict__ spread, const float* __restrict__ eg,
                      const float* __restrict__ ebb, float* __restrict__ wss,
                      const float* __restrict__ x1, const float* __restrict__ pooled,
                      const float* __restrict__ vg, const float* __restrict__ vbb,
                      float* __restrict__ h) {
    if (blockIdx.x == 64) {
        int u = threadIdx.x;
        if (u < 64) {
            float s = 0.f, sqv = 0.f;
            for (int p = 0; p < SPREAD; ++p) {
                s += spread[p * 128 + u];
                sqv += spread[p * 128 + 64 + u];
            }
            const float Mf = (float)((size_t)Bb * Nn * NM1);
            float mean = s / Mf;
            float var = fmaxf(sqv / Mf - mean * mean, 0.f);
            float inv = rsqrtf(var + EPSBN);
            float scale = eg[u] * inv;
            wss[u] = scale;
            wss[64 + u] = ebb[u] - mean * scale;
        }
        return;
    }
    __shared__ float red[256], red2[256];
    int ch = blockIdx.x;
    int t = threadIdx.x;
    float s = 0.f, sqv = 0.f;
    for (int bn = t; bn < Bb * Nn; bn += 256) {
        float v = x1[bn * Uu + ch] + pooled[bn * Uu + ch];
        s += v;
        sqv = fmaf(v, v, sqv);
    }
    red[t] = s;
    red2[t] = sqv;
    __syncthreads();
    for (int off = 128; off; off >>= 1) {
        if (t < off) {
            red[t] += red[t + off];
            red2[t] += red2[t + off];
        }
        __syncthreads();
    }
    const float Mf = (float)(Bb * Nn);
    float mean = red[0] / Mf;
    float var = fmaxf(red2[0] / Mf - mean * mean, 0.f);
    float inv = rsqrtf(var + EPSBN);
    float scale = vg[ch] * inv;
    float shift = vbb[ch] - mean * scale;
    for (int bn = t; bn < Bb * Nn; bn += 256) {
        float v = x1[bn * Uu + ch] + pooled[bn * Uu + ch];
        h[bn * Uu + ch] += lrelu(fmaf(v, scale, shift));
    }
}

__global__ void k_finw(const float* __restrict__ spread, const float* __restrict__ g,
                       const float* __restrict__ bb, float* __restrict__ wss) {
    int u = threadIdx.x;
    float s = 0.f, sq = 0.f;
    for (int p = 0; p < SPREAD; ++p) {
        s += spread[p * 128 + u];
        sq += spread[p * 128 + 64 + u];
    }
    const float Mf = (float)((size_t)Bb * Nn * NM1);
    float mean = s / Mf;
    float var = fmaxf(sq / Mf - mean * mean, 0.f);
    float inv = rsqrtf(var + EPSBN);
    float scale = g[u] * inv;
    wss[u] = scale;
    wss[64 + u] = bb[u] - mean * scale;
}

extern "C" void kernel_launch(void* const* d_in, const int* in_sizes, int n_in,
                              void* d_out, int out_size, void* d_ws, size_t ws_size,
                              hipStream_t stream) {
    const float* x = (const float*)d_in[0];
    const float* adj = (const float*)d_in[1];
    const float* vl0w = (const float*)d_in[2];
    const float* vl0b = (const float*)d_in[3];
    const float* vw1 = (const float*)d_in[4];
    const float* vb1 = (const float*)d_in[5];
    const float* vw2 = (const float*)d_in[6];
    const float* vb2 = (const float*)d_in[7];
    const float* vw3 = (const float*)d_in[8];
    const float* vb3 = (const float*)d_in[9];
    const float* vw4 = (const float*)d_in[10];
    const float* vb4 = (const float*)d_in[11];
    const float* vbng = (const float*)d_in[12];
    const float* vbnb = (const float*)d_in[13];
    const float* e0w = (const float*)d_in[14];
    const float* e0b = (const float*)d_in[15];
    const float* ew = (const float*)d_in[16];
    const float* eb = (const float*)d_in[17];
    const float* ebng = (const float*)d_in[18];
    const float* ebnb = (const float*)d_in[19];
    const float* elw = (const float*)d_in[20];
    const float* elb = (const float*)d_in[21];
    float* out = (float*)d_out;

    f16* w16 = (f16*)d_ws;                      // 3200*13*1024 = 42,598,400 f16
    float* fb = (float*)d_ws + 21299200;
    const size_t NV = 204800;
    float* h = fb;
    float* xv1[3] = {fb + NV, fb + 2 * NV, fb + 3 * NV};
    float* xv2[3] = {fb + 4 * NV, fb + 5 * NV, fb + 6 * NV};
    float* xv3[3] = {fb + 7 * NV, fb + 8 * NV, fb + 9 * NV};
    float* xv4[3] = {fb + 10 * NV, fb + 11 * NV, fb + 12 * NV};
    float* pooled = fb + 13 * NV;
    float* spread = fb + 14 * NV;               // SPREAD*128
    float* wss = spread + SPREAD * 128;         // 128

    const int GRID = Bb * Nn;  // 3200

    // layer 0
    k_xvec<true><<<GRID, 64, 0, stream>>>(x, vl0w, vl0b, h, vw1, vb1, vw2, vb2, vw3,
                                          vb3, vw4, vb4, xv1[0], xv2[0], xv3[0],
                                          xv4[0], spread);
    k_first<<<GRID, 256, 0, stream>>>(adj, ew, eb, e0w, e0b, xv2[0], xv3[0], xv4[0],
                                      pooled, spread);
    k_mid<<<65, 256, 0, stream>>>(spread, ebng, ebnb, wss, xv1[0], pooled, vbng,
                                  vbnb, h);
    // layer 1
    k_xvec<false><<<GRID, 64, 0, stream>>>(x, vl0w, vl0b, h, vw1 + 4096, vb1 + 64,
                                           vw2 + 4096, vb2 + 64, vw3 + 4096, vb3 + 64,
                                           vw4 + 4096, vb4 + 64, xv1[1], xv2[1],
                                           xv3[1], xv4[1], spread);
    k_apply<true><<<GRID, 256, 0, stream>>>(adj, w16, ew, eb, e0w, e0b, xv3[0],
                                            xv4[0], xv2[1], wss, pooled);
    k_p1s<<<GRID, 256, 0, stream>>>(w16, ew + 4096, eb + 64, xv3[1], xv4[1], spread);
    k_mid<<<65, 256, 0, stream>>>(spread, ebng + 64, ebnb + 64, wss, xv1[1], pooled,
                                  vbng + 64, vbnb + 64, h);
    // layer 2
    k_xvec<false><<<GRID, 64, 0, stream>>>(x, vl0w, vl0b, h, vw1 + 8192, vb1 + 128,
                                           vw2 + 8192, vb2 + 128, vw3 + 8192,
                                           vb3 + 128, vw4 + 8192, vb4 + 128, xv1[2],
                                           xv2[2], xv3[2], xv4[2], spread);
    k_apply<false><<<GRID, 256, 0, stream>>>(adj, w16, ew + 4096, eb + 64, e0w, e0b,
                                             xv3[1], xv4[1], xv2[2], wss, pooled);
    k_p1s<<<GRID, 256, 0, stream>>>(w16, ew + 8192, eb + 128, xv3[2], xv4[2], spread);
    k_mid<<<65, 256, 0, stream>>>(spread, ebng + 128, ebnb + 128, wss, xv1[2], pooled,
                                  vbng + 128, vbnb + 128, h);
    k_finw<<<1, 64, 0, stream>>>(spread, ebng + 128, ebnb + 128, wss);
    k_last<<<GRID, 256, 0, stream>>>(w16, ew + 8192, eb + 128, xv3[2], xv4[2], wss,
                                     elw, elb, out);
}

// Round 6
// 450.837 us; speedup vs baseline: 1.4336x; 1.2809x over previous
//
#include <hip/hip_runtime.h>

#define Bb 16
#define Nn 200
#define NM1 199
#define Uu 64
#define EPSBN 1e-5f
#define SLOPE 0.01f
#define SPREAD 64
#define ETS 72   // f16 elems per Et row (64 + 8 pad)
#define ZSH 36   // f32 elems per zbuf row (32 + 4 pad), 2-phase transform

typedef _Float16 f16;
typedef __attribute__((ext_vector_type(8))) _Float16 f16x8;
typedef __attribute__((ext_vector_type(2))) _Float16 f16x2;
typedef __attribute__((ext_vector_type(4))) float floatx4;

// w16 tile layout: per (bn, mt) a 1024-f16 tile; chunk l (16 B) == lane l's
// A-fragment (KB0 at +0, KB1 at +512 elems). Wave-contiguous 1 KB per access.
__device__ __forceinline__ size_t tbase(int bn, int mt) {
    return ((size_t)bn * 13 + mt) * 1024;
}

__device__ __forceinline__ float lrelu(float v) { return v > 0.f ? v : SLOPE * v; }
__device__ __forceinline__ int dstcol(int n, int k) { return k < n ? k : k + 1; }
__device__ __forceinline__ float sigm(float v) { return 1.f / (1.f + __expf(-v)); }

__device__ __forceinline__ f16x8 ntload8(const f16* p) {
    return __builtin_nontemporal_load((const f16x8*)p);
}
__device__ __forceinline__ void ntstore8(f16* p, f16x8 v) {
    __builtin_nontemporal_store(v, (f16x8*)p);
}

__device__ __forceinline__ void stageEt(const float* __restrict__ ew, f16* Et, int tid) {
    int u = tid & 63, g = tid >> 6;
#pragma unroll
    for (int pp = 0; pp < 8; ++pp) {
        int jp = g + pp * 4;
        f16x2 pk;
        pk.x = (f16)ew[(2 * jp) * Uu + u];
        pk.y = (f16)ew[(2 * jp + 1) * Uu + u];
        *(f16x2*)&Et[u * ETS + 2 * jp] = pk;
    }
}

// x-vec projections; L0 also computes h from x; block 0 zeroes spread
template <bool L0>
__global__ void k_xvec(const float* __restrict__ xin, const float* __restrict__ l0w,
                       const float* __restrict__ l0b, float* __restrict__ h,
                       const float* __restrict__ w1, const float* __restrict__ b1,
                       const float* __restrict__ w2, const float* __restrict__ b2,
                       const float* __restrict__ w3, const float* __restrict__ b3,
                       const float* __restrict__ w4, const float* __restrict__ b4,
                       float* __restrict__ x1, float* __restrict__ x2,
                       float* __restrict__ x3, float* __restrict__ x4,
                       float* __restrict__ spread) {
    __shared__ float hrow[Uu];
    int bn = blockIdx.x;
    int u = threadIdx.x;
    if (blockIdx.x == 0) {
        for (int t = u; t < SPREAD * 128; t += Uu) spread[t] = 0.f;
    }
    if (L0) {
        float v = fmaf(xin[bn * 2], l0w[u], fmaf(xin[bn * 2 + 1], l0w[Uu + u], l0b[u]));
        v = lrelu(v);
        hrow[u] = v;
        h[bn * Uu + u] = v;
    } else {
        hrow[u] = h[bn * Uu + u];
    }
    __syncthreads();
    float a1 = b1[u], a2 = b2[u], a3 = b3[u], a4 = b4[u];
#pragma unroll 8
    for (int j = 0; j < Uu; ++j) {
        float hv = hrow[j];
        a1 = fmaf(hv, w1[j * Uu + u], a1);
        a2 = fmaf(hv, w2[j * Uu + u], a2);
        a3 = fmaf(hv, w3[j * Uu + u], a3);
        a4 = fmaf(hv, w4[j * Uu + u], a4);
    }
    x1[bn * Uu + u] = a1;
    x2[bn * Uu + u] = a2;
    x3[bn * Uu + u] = a3;
    x4[bn * Uu + u] = a4;
}

// layer-0 stats + pooled; w0 recomputed from adj, never stored
__global__ __launch_bounds__(256, 3) void k_first(
    const float* __restrict__ adj,
    const float* __restrict__ ew1, const float* __restrict__ eb1,
    const float* __restrict__ e0w, const float* __restrict__ e0b,
    const float* __restrict__ x2a, const float* __restrict__ x3a,
    const float* __restrict__ x4a,
    float* __restrict__ pooled, float* __restrict__ spread) {
    __shared__ __align__(16) f16 Et[Uu * ETS];
    __shared__ float c2s[Uu];
    __shared__ float sred[128];
    __shared__ float pbuf[4][Uu];
    int bn = blockIdx.x;
    int b = bn / Nn, n = bn % Nn;
    int tid = threadIdx.x;
    int l = tid & 63, wv = tid >> 6;
    int r16 = l & 15, q = l >> 4;
    stageEt(ew1, Et, tid);
    if (tid < Uu) c2s[tid] = eb1[tid] + x3a[(size_t)bn * Uu + tid];
    if (tid < 128) sred[tid] = 0.f;
    __syncthreads();

    float e0r[2][8], e0br[2][8];
#pragma unroll
    for (int g2 = 0; g2 < 2; ++g2)
#pragma unroll
        for (int j = 0; j < 8; ++j) {
            int ch = g2 * 32 + q * 8 + j;
            e0r[g2][j] = e0w[ch];
            e0br[g2][j] = e0b[ch];
        }

    const float* adjrow = adj + (size_t)bn * Nn;
    float sum[4] = {0, 0, 0, 0}, sq[4] = {0, 0, 0, 0};
    float pm[2][8];
#pragma unroll
    for (int g2 = 0; g2 < 2; ++g2)
#pragma unroll
        for (int j = 0; j < 8; ++j) pm[g2][j] = -3.402823e38f;

    for (int mt = wv; mt < 13; mt += 4) {
        int row = mt * 16 + r16;
        bool rv = row < NM1;
        int dst = dstcol(n, rv ? row : 0);
        float adv = rv ? adjrow[dst] : 0.f;
        float w0[2][8];
        f16x8 A0, A1;
#pragma unroll
        for (int j = 0; j < 8; ++j) {
            w0[0][j] = lrelu(fmaf(adv, e0r[0][j], e0br[0][j]));
            w0[1][j] = lrelu(fmaf(adv, e0r[1][j], e0br[1][j]));
            A0[j] = (f16)w0[0][j];
            A1[j] = (f16)w0[1][j];
        }
        floatx4 acc[4];
#pragma unroll
        for (int nt = 0; nt < 4; ++nt) {
            f16x8 B0 = *(const f16x8*)&Et[(nt * 16 + r16) * ETS + q * 8];
            f16x8 B1 = *(const f16x8*)&Et[(nt * 16 + r16) * ETS + 32 + q * 8];
            acc[nt] = (floatx4){0, 0, 0, 0};
            acc[nt] = __builtin_amdgcn_mfma_f32_16x16x32_f16(A0, B0, acc[nt], 0, 0, 0);
            acc[nt] = __builtin_amdgcn_mfma_f32_16x16x32_f16(A1, B1, acc[nt], 0, 0, 0);
        }
#pragma unroll
        for (int rr = 0; rr < 4; ++rr) {
            int k = mt * 16 + q * 4 + rr;
            if (k < NM1) {
                int d2 = dstcol(n, k);
                const float* x4r = x4a + (size_t)(b * Nn + d2) * Uu;
#pragma unroll
                for (int nt = 0; nt < 4; ++nt) {
                    int u = nt * 16 + r16;
                    float z = acc[nt][rr] + c2s[u] + x4r[u];
                    sum[nt] += z;
                    sq[nt] = fmaf(z, z, sq[nt]);
                }
            }
        }
        if (rv) {
            const float* x2r = x2a + (size_t)(b * Nn + dst) * Uu;
#pragma unroll
            for (int g2 = 0; g2 < 2; ++g2) {
                float xv[8];
                *(float4*)&xv[0] = *(const float4*)(x2r + g2 * 32 + q * 8);
                *(float4*)&xv[4] = *(const float4*)(x2r + g2 * 32 + q * 8 + 4);
#pragma unroll
                for (int j = 0; j < 8; ++j)
                    pm[g2][j] = fmaxf(pm[g2][j], sigm(w0[g2][j]) * xv[j]);
            }
        }
    }
#pragma unroll
    for (int nt = 0; nt < 4; ++nt) {
        sum[nt] += __shfl_xor(sum[nt], 16, 64);
        sum[nt] += __shfl_xor(sum[nt], 32, 64);
        sq[nt] += __shfl_xor(sq[nt], 16, 64);
        sq[nt] += __shfl_xor(sq[nt], 32, 64);
    }
    if (l < 16) {
#pragma unroll
        for (int nt = 0; nt < 4; ++nt) {
            atomicAdd(&sred[nt * 16 + l], sum[nt]);
            atomicAdd(&sred[64 + nt * 16 + l], sq[nt]);
        }
    }
#pragma unroll
    for (int g2 = 0; g2 < 2; ++g2)
#pragma unroll
        for (int j = 0; j < 8; ++j) {
            float v = pm[g2][j];
            v = fmaxf(v, __shfl_xor(v, 1, 64));
            v = fmaxf(v, __shfl_xor(v, 2, 64));
            v = fmaxf(v, __shfl_xor(v, 4, 64));
            v = fmaxf(v, __shfl_xor(v, 8, 64));
            pm[g2][j] = v;
        }
    if (r16 == 0) {
#pragma unroll
        for (int g2 = 0; g2 < 2; ++g2)
#pragma unroll
            for (int j = 0; j < 8; ++j) pbuf[wv][g2 * 32 + q * 8 + j] = pm[g2][j];
    }
    __syncthreads();
    if (tid < 128) atomicAdd(&spread[(bn & (SPREAD - 1)) * 128 + tid], sred[tid]);
    if (tid < Uu)
        pooled[(size_t)bn * Uu + tid] =
            fmaxf(fmaxf(pbuf[0][tid], pbuf[1][tid]), fmaxf(pbuf[2][tid], pbuf[3][tid]));
}

// apply BN(i)+residual -> wnew (NT tile store). Lean: params in LDS, A prefetch.
template <bool FIRST>
__global__ __launch_bounds__(256, 3) void k_apply(
    const float* __restrict__ adj, f16* __restrict__ w16,
    const float* __restrict__ ew1, const float* __restrict__ eb1,
    const float* __restrict__ e0w, const float* __restrict__ e0b,
    const float* __restrict__ x3a, const float* __restrict__ x4a,
    const float* __restrict__ wss) {
    __shared__ __align__(16) f16 Et1[Uu * ETS];
    __shared__ __align__(16) float zbuf[4][16 * ZSH];
    __shared__ __align__(16) float c1s[Uu];
    __shared__ __align__(16) float wssL[128];
    __shared__ __align__(16) float e0L[128];
    int bn = blockIdx.x;
    int b = bn / Nn, n = bn % Nn;
    int tid = threadIdx.x;
    int l = tid & 63, wv = tid >> 6;
    int r16 = l & 15, q = l >> 4;
    stageEt(ew1, Et1, tid);
    if (tid < Uu) c1s[tid] = eb1[tid] + x3a[(size_t)bn * Uu + tid];
    if (tid < 128) wssL[tid] = wss[tid];
    if (FIRST && tid < Uu) {
        e0L[tid] = e0w[tid];
        e0L[64 + tid] = e0b[tid];
    }
    __syncthreads();

    const float* adjrow = adj + (size_t)bn * Nn;
    float* zb = zbuf[wv];

    // A prefetch (register double buffer)
    float advc = 0.f;
    f16x8 A0c = (f16x8){0, 0, 0, 0, 0, 0, 0, 0}, A1c = A0c;
    {
        int row = wv * 16 + r16;
        if (FIRST) {
            if (row < NM1) advc = adjrow[dstcol(n, row)];
        } else {
            size_t tb = tbase(bn, wv);
            A0c = ntload8(w16 + tb + (size_t)l * 8);
            A1c = ntload8(w16 + tb + 512 + (size_t)l * 8);
        }
    }

    for (int mt = wv; mt < 13; mt += 4) {
        int row = mt * 16 + r16;
        bool rv = row < NM1;
        int dst = dstcol(n, rv ? row : 0);
        size_t tb = tbase(bn, mt);
        // prefetch next
        float advn = 0.f;
        f16x8 A0n = (f16x8){0, 0, 0, 0, 0, 0, 0, 0}, A1n = A0n;
        if (mt + 4 < 13) {
            int rown = (mt + 4) * 16 + r16;
            if (FIRST) {
                if (rown < NM1) advn = adjrow[dstcol(n, rown)];
            } else {
                size_t tbn = tbase(bn, mt + 4);
                A0n = ntload8(w16 + tbn + (size_t)l * 8);
                A1n = ntload8(w16 + tbn + 512 + (size_t)l * 8);
            }
        }
        f16x8 A0, A1;
        float wold[2][8];
        if (FIRST) {
            float adv = advc;  // zero for invalid rows
#pragma unroll
            for (int g2 = 0; g2 < 2; ++g2) {
                float ewv[8], ebv[8];
                *(float4*)&ewv[0] = *(const float4*)&e0L[g2 * 32 + q * 8];
                *(float4*)&ewv[4] = *(const float4*)&e0L[g2 * 32 + q * 8 + 4];
                *(float4*)&ebv[0] = *(const float4*)&e0L[64 + g2 * 32 + q * 8];
                *(float4*)&ebv[4] = *(const float4*)&e0L[64 + g2 * 32 + q * 8 + 4];
#pragma unroll
                for (int j = 0; j < 8; ++j)
                    wold[g2][j] = lrelu(fmaf(adv, ewv[j], ebv[j]));
            }
#pragma unroll
            for (int j = 0; j < 8; ++j) {
                A0[j] = (f16)wold[0][j];
                A1[j] = (f16)wold[1][j];
            }
        } else {
            A0 = A0c;
            A1 = A1c;
#pragma unroll
            for (int j = 0; j < 8; ++j) {
                wold[0][j] = (float)A0[j];
                wold[1][j] = (float)A1[j];
            }
        }
        floatx4 acc[4];
#pragma unroll
        for (int nt = 0; nt < 4; ++nt) {
            f16x8 B0 = *(const f16x8*)&Et1[(nt * 16 + r16) * ETS + q * 8];
            f16x8 B1 = *(const f16x8*)&Et1[(nt * 16 + r16) * ETS + 32 + q * 8];
            acc[nt] = (floatx4){0, 0, 0, 0};
            acc[nt] = __builtin_amdgcn_mfma_f32_16x16x32_f16(A0, B0, acc[nt], 0, 0, 0);
            acc[nt] = __builtin_amdgcn_mfma_f32_16x16x32_f16(A1, B1, acc[nt], 0, 0, 0);
        }
        // C -> A transform, 2 phases of 32 channels (wave-private zbuf, in-order DS)
        float zA[2][8];
#pragma unroll
        for (int rr = 0; rr < 4; ++rr) {
            int zr = q * 4 + rr;
            zb[zr * ZSH + r16] = acc[0][rr];
            zb[zr * ZSH + 16 + r16] = acc[1][rr];
        }
        *(float4*)&zA[0][0] = *(const float4*)&zb[r16 * ZSH + q * 8];
        *(float4*)&zA[0][4] = *(const float4*)&zb[r16 * ZSH + q * 8 + 4];
#pragma unroll
        for (int rr = 0; rr < 4; ++rr) {
            int zr = q * 4 + rr;
            zb[zr * ZSH + r16] = acc[2][rr];
            zb[zr * ZSH + 16 + r16] = acc[3][rr];
        }
        *(float4*)&zA[1][0] = *(const float4*)&zb[r16 * ZSH + q * 8];
        *(float4*)&zA[1][4] = *(const float4*)&zb[r16 * ZSH + q * 8 + 4];

        float x4v[2][8] = {{0, 0, 0, 0, 0, 0, 0, 0}, {0, 0, 0, 0, 0, 0, 0, 0}};
        if (rv) {
            const float* x4r = x4a + (size_t)(b * Nn + dst) * Uu;
            *(float4*)&x4v[0][0] = *(const float4*)(x4r + q * 8);
            *(float4*)&x4v[0][4] = *(const float4*)(x4r + q * 8 + 4);
            *(float4*)&x4v[1][0] = *(const float4*)(x4r + 32 + q * 8);
            *(float4*)&x4v[1][4] = *(const float4*)(x4r + 32 + q * 8 + 4);
        }
        f16x8 W0, W1;
#pragma unroll
        for (int g2 = 0; g2 < 2; ++g2) {
            float scv[8], shv[8], c1v[8];
            *(float4*)&scv[0] = *(const float4*)&wssL[g2 * 32 + q * 8];
            *(float4*)&scv[4] = *(const float4*)&wssL[g2 * 32 + q * 8 + 4];
            *(float4*)&shv[0] = *(const float4*)&wssL[64 + g2 * 32 + q * 8];
            *(float4*)&shv[4] = *(const float4*)&wssL[64 + g2 * 32 + q * 8 + 4];
            *(float4*)&c1v[0] = *(const float4*)&c1s[g2 * 32 + q * 8];
            *(float4*)&c1v[4] = *(const float4*)&c1s[g2 * 32 + q * 8 + 4];
#pragma unroll
            for (int j = 0; j < 8; ++j) {
                float z = zA[g2][j] + c1v[j] + x4v[g2][j];
                float wn = wold[g2][j] + lrelu(fmaf(z, scv[j], shv[j]));
                if (g2 == 0) W0[j] = (f16)wn;
                else W1[j] = (f16)wn;
            }
        }
        ntstore8(w16 + tb + (size_t)l * 8, W0);
        ntstore8(w16 + tb + 512 + (size_t)l * 8, W1);
        advc = advn;
        A0c = A0n;
        A1c = A1n;
    }
}

// stats pass (+ optional pool of sig(w)*x2): NT-read w16, GEMM(Et), BN stats of z
template <bool POOL>
__global__ __launch_bounds__(256, 3) void k_p1s(
    const f16* __restrict__ w16, const float* __restrict__ ew2,
    const float* __restrict__ eb2, const float* __restrict__ x3b,
    const float* __restrict__ x4b, const float* __restrict__ x2b,
    float* __restrict__ spread, float* __restrict__ pooled) {
    __shared__ __align__(16) f16 Et[Uu * ETS];
    __shared__ float c2s[Uu];
    __shared__ float sred[128];
    __shared__ float pbuf[4][Uu];
    int bn = blockIdx.x;
    int b = bn / Nn, n = bn % Nn;
    int tid = threadIdx.x;
    int l = tid & 63, wv = tid >> 6;
    int r16 = l & 15, q = l >> 4;
    stageEt(ew2, Et, tid);
    if (tid < Uu) c2s[tid] = eb2[tid] + x3b[(size_t)bn * Uu + tid];
    if (tid < 128) sred[tid] = 0.f;
    __syncthreads();

    float sum[4] = {0, 0, 0, 0}, sq[4] = {0, 0, 0, 0};
    float pm[2][8];
    if (POOL) {
#pragma unroll
        for (int g2 = 0; g2 < 2; ++g2)
#pragma unroll
            for (int j = 0; j < 8; ++j) pm[g2][j] = -3.402823e38f;
    }

    f16x8 A0c, A1c;
    {
        size_t tb = tbase(bn, wv);
        A0c = ntload8(w16 + tb + (size_t)l * 8);
        A1c = ntload8(w16 + tb + 512 + (size_t)l * 8);
    }

    for (int mt = wv; mt < 13; mt += 4) {
        int row = mt * 16 + r16;
        bool rv = row < NM1;
        f16x8 A0n = (f16x8){0, 0, 0, 0, 0, 0, 0, 0}, A1n = A0n;
        if (mt + 4 < 13) {
            size_t tbn = tbase(bn, mt + 4);
            A0n = ntload8(w16 + tbn + (size_t)l * 8);
            A1n = ntload8(w16 + tbn + 512 + (size_t)l * 8);
        }
        f16x8 A0 = A0c, A1 = A1c;
        floatx4 acc[4];
#pragma unroll
        for (int nt = 0; nt < 4; ++nt) {
            f16x8 B0 = *(const f16x8*)&Et[(nt * 16 + r16) * ETS + q * 8];
            f16x8 B1 = *(const f16x8*)&Et[(nt * 16 + r16) * ETS + 32 + q * 8];
            acc[nt] = (floatx4){0, 0, 0, 0};
            acc[nt] = __builtin_amdgcn_mfma_f32_16x16x32_f16(A0, B0, acc[nt], 0, 0, 0);
            acc[nt] = __builtin_amdgcn_mfma_f32_16x16x32_f16(A1, B1, acc[nt], 0, 0, 0);
        }
#pragma unroll
        for (int rr = 0; rr < 4; ++rr) {
            int k = mt * 16 + q * 4 + rr;
            if (k < NM1) {
                int d2 = dstcol(n, k);
                const float* x4r = x4b + (size_t)(b * Nn + d2) * Uu;
#pragma unroll
                for (int nt = 0; nt < 4; ++nt) {
                    int u = nt * 16 + r16;
                    float z = acc[nt][rr] + c2s[u] + x4r[u];
                    sum[nt] += z;
                    sq[nt] = fmaf(z, z, sq[nt]);
                }
            }
        }
        if (POOL && rv) {
            int dst = dstcol(n, row);
            const float* x2r = x2b + (size_t)(b * Nn + dst) * Uu;
#pragma unroll
            for (int g2 = 0; g2 < 2; ++g2) {
                float xv[8];
                *(float4*)&xv[0] = *(const float4*)(x2r + g2 * 32 + q * 8);
                *(float4*)&xv[4] = *(const float4*)(x2r + g2 * 32 + q * 8 + 4);
#pragma unroll
                for (int j = 0; j < 8; ++j) {
                    float wv_ = (float)(g2 == 0 ? A0[j] : A1[j]);
                    pm[g2][j] = fmaxf(pm[g2][j], sigm(wv_) * xv[j]);
                }
            }
        }
        A0c = A0n;
        A1c = A1n;
    }
#pragma unroll
    for (int nt = 0; nt < 4; ++nt) {
        sum[nt] += __shfl_xor(sum[nt], 16, 64);
        sum[nt] += __shfl_xor(sum[nt], 32, 64);
        sq[nt] += __shfl_xor(sq[nt], 16, 64);
        sq[nt] += __shfl_xor(sq[nt], 32, 64);
    }
    if (l < 16) {
#pragma unroll
        for (int nt = 0; nt < 4; ++nt) {
            atomicAdd(&sred[nt * 16 + l], sum[nt]);
            atomicAdd(&sred[64 + nt * 16 + l], sq[nt]);
        }
    }
    if (POOL) {
#pragma unroll
        for (int g2 = 0; g2 < 2; ++g2)
#pragma unroll
            for (int j = 0; j < 8; ++j) {
                float v = pm[g2][j];
                v = fmaxf(v, __shfl_xor(v, 1, 64));
                v = fmaxf(v, __shfl_xor(v, 2, 64));
                v = fmaxf(v, __shfl_xor(v, 4, 64));
                v = fmaxf(v, __shfl_xor(v, 8, 64));
                pm[g2][j] = v;
            }
        if (r16 == 0) {
#pragma unroll
            for (int g2 = 0; g2 < 2; ++g2)
#pragma unroll
                for (int j = 0; j < 8; ++j) pbuf[wv][g2 * 32 + q * 8 + j] = pm[g2][j];
        }
    }
    __syncthreads();
    if (tid < 128) atomicAdd(&spread[(bn & (SPREAD - 1)) * 128 + tid], sred[tid]);
    if (POOL && tid < Uu)
        pooled[(size_t)bn * Uu + tid] =
            fmaxf(fmaxf(pbuf[0][tid], pbuf[1][tid]), fmaxf(pbuf[2][tid], pbuf[3][tid]));
}

// last: apply BN(2)+residual, dot with e_lin1, scatter to out
__global__ __launch_bounds__(256, 3) void k_last(
    const f16* __restrict__ w16, const float* __restrict__ ew1,
    const float* __restrict__ eb1, const float* __restrict__ x3a,
    const float* __restrict__ x4a, const float* __restrict__ wss,
    const float* __restrict__ elw, const float* __restrict__ elb,
    float* __restrict__ out) {
    __shared__ __align__(16) f16 Et1[Uu * ETS];
    __shared__ __align__(16) float zbuf[4][16 * ZSH];
    __shared__ __align__(16) float c1s[Uu];
    __shared__ __align__(16) float wssL[128];
    __shared__ __align__(16) float elwL[Uu];
    int bn = blockIdx.x;
    int b = bn / Nn, n = bn % Nn;
    int tid = threadIdx.x;
    int l = tid & 63, wv = tid >> 6;
    int r16 = l & 15, q = l >> 4;
    stageEt(ew1, Et1, tid);
    if (tid < Uu) {
        c1s[tid] = eb1[tid] + x3a[(size_t)bn * Uu + tid];
        elwL[tid] = elw[tid];
    }
    if (tid < 128) wssL[tid] = wss[tid];
    __syncthreads();

    float elb0 = elb[0];
    float* zb = zbuf[wv];

    f16x8 A0c, A1c;
    {
        size_t tb = tbase(bn, wv);
        A0c = ntload8(w16 + tb + (size_t)l * 8);
        A1c = ntload8(w16 + tb + 512 + (size_t)l * 8);
    }

    for (int mt = wv; mt < 13; mt += 4) {
        int row = mt * 16 + r16;
        bool rv = row < NM1;
        int dst = dstcol(n, rv ? row : 0);
        f16x8 A0n = (f16x8){0, 0, 0, 0, 0, 0, 0, 0}, A1n = A0n;
        if (mt + 4 < 13) {
            size_t tbn = tbase(bn, mt + 4);
            A0n = ntload8(w16 + tbn + (size_t)l * 8);
            A1n = ntload8(w16 + tbn + 512 + (size_t)l * 8);
        }
        f16x8 A0 = A0c, A1 = A1c;
        float wold[2][8];
#pragma unroll
        for (int j = 0; j < 8; ++j) {
            wold[0][j] = (float)A0[j];
            wold[1][j] = (float)A1[j];
        }
        floatx4 acc[4];
#pragma unroll
        for (int nt = 0; nt < 4; ++nt) {
            f16x8 B0 = *(const f16x8*)&Et1[(nt * 16 + r16) * ETS + q * 8];
            f16x8 B1 = *(const f16x8*)&Et1[(nt * 16 + r16) * ETS + 32 + q * 8];
            acc[nt] = (floatx4){0, 0, 0, 0};
            acc[nt] = __builtin_amdgcn_mfma_f32_16x16x32_f16(A0, B0, acc[nt], 0, 0, 0);
            acc[nt] = __builtin_amdgcn_mfma_f32_16x16x32_f16(A1, B1, acc[nt], 0, 0, 0);
        }
        float zA[2][8];
#pragma unroll
        for (int rr = 0; rr < 4; ++rr) {
            int zr = q * 4 + rr;
            zb[zr * ZSH + r16] = acc[0][rr];
            zb[zr * ZSH + 16 + r16] = acc[1][rr];
        }
        *(float4*)&zA[0][0] = *(const float4*)&zb[r16 * ZSH + q * 8];
        *(float4*)&zA[0][4] = *(const float4*)&zb[r16 * ZSH + q * 8 + 4];
#pragma unroll
        for (int rr = 0; rr < 4; ++rr) {
            int zr = q * 4 + rr;
            zb[zr * ZSH + r16] = acc[2][rr];
            zb[zr * ZSH + 16 + r16] = acc[3][rr];
        }
        *(float4*)&zA[1][0] = *(const float4*)&zb[r16 * ZSH + q * 8];
        *(float4*)&zA[1][4] = *(const float4*)&zb[r16 * ZSH + q * 8 + 4];

        float x4v[2][8] = {{0, 0, 0, 0, 0, 0, 0, 0}, {0, 0, 0, 0, 0, 0, 0, 0}};
        if (rv) {
            const float* x4r = x4a + (size_t)(b * Nn + dst) * Uu;
            *(float4*)&x4v[0][0] = *(const float4*)(x4r + q * 8);
            *(float4*)&x4v[0][4] = *(const float4*)(x4r + q * 8 + 4);
            *(float4*)&x4v[1][0] = *(const float4*)(x4r + 32 + q * 8);
            *(float4*)&x4v[1][4] = *(const float4*)(x4r + 32 + q * 8 + 4);
        }
        float t = 0.f;
#pragma unroll
        for (int g2 = 0; g2 < 2; ++g2) {
            float scv[8], shv[8], c1v[8], elv[8];
            *(float4*)&scv[0] = *(const float4*)&wssL[g2 * 32 + q * 8];
            *(float4*)&scv[4] = *(const float4*)&wssL[g2 * 32 + q * 8 + 4];
            *(float4*)&shv[0] = *(const float4*)&wssL[64 + g2 * 32 + q * 8];
            *(float4*)&shv[4] = *(const float4*)&wssL[64 + g2 * 32 + q * 8 + 4];
            *(float4*)&c1v[0] = *(const float4*)&c1s[g2 * 32 + q * 8];
            *(float4*)&c1v[4] = *(const float4*)&c1s[g2 * 32 + q * 8 + 4];
            *(float4*)&elv[0] = *(const float4*)&elwL[g2 * 32 + q * 8];
            *(float4*)&elv[4] = *(const float4*)&elwL[g2 * 32 + q * 8 + 4];
#pragma unroll
            for (int j = 0; j < 8; ++j) {
                float z = zA[g2][j] + c1v[j] + x4v[g2][j];
                float wn = wold[g2][j] + lrelu(fmaf(z, scv[j], shv[j]));
                t = fmaf(wn, elv[j], t);
            }
        }
        t += __shfl_xor(t, 16, 64);
        t += __shfl_xor(t, 32, 64);
        if (q == 0 && rv) out[(size_t)bn * Nn + dst] = t + elb0;
        A0c = A0n;
        A1c = A1n;
    }
    if (tid == 0) out[(size_t)bn * Nn + n] = 0.f;
}

// finw (block 64) + hup (blocks 0..63)
__global__ void k_mid(const float* __restrict__ spread, const float* __restrict__ eg,
                      const float* __restrict__ ebb, float* __restrict__ wss,
                      const float* __restrict__ x1, const float* __restrict__ pooled,
                      const float* __restrict__ vg, const float* __restrict__ vbb,
                      float* __restrict__ h) {
    if (blockIdx.x == 64) {
        int u = threadIdx.x;
        if (u < 64) {
            float s = 0.f, sqv = 0.f;
            for (int p = 0; p < SPREAD; ++p) {
                s += spread[p * 128 + u];
                sqv += spread[p * 128 + 64 + u];
            }
            const float Mf = (float)((size_t)Bb * Nn * NM1);
            float mean = s / Mf;
            float var = fmaxf(sqv / Mf - mean * mean, 0.f);
            float inv = rsqrtf(var + EPSBN);
            float scale = eg[u] * inv;
            wss[u] = scale;
            wss[64 + u] = ebb[u] - mean * scale;
        }
        return;
    }
    __shared__ float red[256], red2[256];
    int ch = blockIdx.x;
    int t = threadIdx.x;
    float s = 0.f, sqv = 0.f;
    for (int bn = t; bn < Bb * Nn; bn += 256) {
        float v = x1[bn * Uu + ch] + pooled[bn * Uu + ch];
        s += v;
        sqv = fmaf(v, v, sqv);
    }
    red[t] = s;
    red2[t] = sqv;
    __syncthreads();
    for (int off = 128; off; off >>= 1) {
        if (t < off) {
            red[t] += red[t + off];
            red2[t] += red2[t + off];
        }
        __syncthreads();
    }
    const float Mf = (float)(Bb * Nn);
    float mean = red[0] / Mf;
    float var = fmaxf(red2[0] / Mf - mean * mean, 0.f);
    float inv = rsqrtf(var + EPSBN);
    float scale = vg[ch] * inv;
    float shift = vbb[ch] - mean * scale;
    for (int bn = t; bn < Bb * Nn; bn += 256) {
        float v = x1[bn * Uu + ch] + pooled[bn * Uu + ch];
        h[bn * Uu + ch] += lrelu(fmaf(v, scale, shift));
    }
}

__global__ void k_finw(const float* __restrict__ spread, const float* __restrict__ g,
                       const float* __restrict__ bb, float* __restrict__ wss) {
    int u = threadIdx.x;
    float s = 0.f, sq = 0.f;
    for (int p = 0; p < SPREAD; ++p) {
        s += spread[p * 128 + u];
        sq += spread[p * 128 + 64 + u];
    }
    const float Mf = (float)((size_t)Bb * Nn * NM1);
    float mean = s / Mf;
    float var = fmaxf(sq / Mf - mean * mean, 0.f);
    float inv = rsqrtf(var + EPSBN);
    float scale = g[u] * inv;
    wss[u] = scale;
    wss[64 + u] = bb[u] - mean * scale;
}

extern "C" void kernel_launch(void* const* d_in, const int* in_sizes, int n_in,
                              void* d_out, int out_size, void* d_ws, size_t ws_size,
                              hipStream_t stream) {
    const float* x = (const float*)d_in[0];
    const float* adj = (const float*)d_in[1];
    const float* vl0w = (const float*)d_in[2];
    const float* vl0b = (const float*)d_in[3];
    const float* vw1 = (const float*)d_in[4];
    const float* vb1 = (const float*)d_in[5];
    const float* vw2 = (const float*)d_in[6];
    const float* vb2 = (const float*)d_in[7];
    const float* vw3 = (const float*)d_in[8];
    const float* vb3 = (const float*)d_in[9];
    const float* vw4 = (const float*)d_in[10];
    const float* vb4 = (const float*)d_in[11];
    const float* vbng = (const float*)d_in[12];
    const float* vbnb = (const float*)d_in[13];
    const float* e0w = (const float*)d_in[14];
    const float* e0b = (const float*)d_in[15];
    const float* ew = (const float*)d_in[16];
    const float* eb = (const float*)d_in[17];
    const float* ebng = (const float*)d_in[18];
    const float* ebnb = (const float*)d_in[19];
    const float* elw = (const float*)d_in[20];
    const float* elb = (const float*)d_in[21];
    float* out = (float*)d_out;

    f16* w16 = (f16*)d_ws;                      // 3200*13*1024 = 42,598,400 f16
    float* fb = (float*)d_ws + 21299200;
    const size_t NV = 204800;
    float* h = fb;
    float* xv1[3] = {fb + NV, fb + 2 * NV, fb + 3 * NV};
    float* xv2[3] = {fb + 4 * NV, fb + 5 * NV, fb + 6 * NV};
    float* xv3[3] = {fb + 7 * NV, fb + 8 * NV, fb + 9 * NV};
    float* xv4[3] = {fb + 10 * NV, fb + 11 * NV, fb + 12 * NV};
    float* pooled = fb + 13 * NV;
    float* spread = fb + 14 * NV;               // SPREAD*128
    float* wss = spread + SPREAD * 128;         // 128

    const int GRID = Bb * Nn;  // 3200

    // layer 0
    k_xvec<true><<<GRID, 64, 0, stream>>>(x, vl0w, vl0b, h, vw1, vb1, vw2, vb2, vw3,
                                          vb3, vw4, vb4, xv1[0], xv2[0], xv3[0],
                                          xv4[0], spread);
    k_first<<<GRID, 256, 0, stream>>>(adj, ew, eb, e0w, e0b, xv2[0], xv3[0], xv4[0],
                                      pooled, spread);
    k_mid<<<65, 256, 0, stream>>>(spread, ebng, ebnb, wss, xv1[0], pooled, vbng,
                                  vbnb, h);
    // layer 1
    k_xvec<false><<<GRID, 64, 0, stream>>>(x, vl0w, vl0b, h, vw1 + 4096, vb1 + 64,
                                           vw2 + 4096, vb2 + 64, vw3 + 4096, vb3 + 64,
                                           vw4 + 4096, vb4 + 64, xv1[1], xv2[1],
                                           xv3[1], xv4[1], spread);
    k_apply<true><<<GRID, 256, 0, stream>>>(adj, w16, ew, eb, e0w, e0b, xv3[0],
                                            xv4[0], wss);
    k_p1s<true><<<GRID, 256, 0, stream>>>(w16, ew + 4096, eb + 64, xv3[1], xv4[1],
                                          xv2[1], spread, pooled);
    k_mid<<<65, 256, 0, stream>>>(spread, ebng + 64, ebnb + 64, wss, xv1[1], pooled,
                                  vbng + 64, vbnb + 64, h);
    // layer 2 (h-path after layer 2 is dead: no pool, no h update)
    k_xvec<false><<<GRID, 64, 0, stream>>>(x, vl0w, vl0b, h, vw1 + 8192, vb1 + 128,
                                           vw2 + 8192, vb2 + 128, vw3 + 8192,
                                           vb3 + 128, vw4 + 8192, vb4 + 128, xv1[2],
                                           xv2[2], xv3[2], xv4[2], spread);
    k_apply<false><<<GRID, 256, 0, stream>>>(adj, w16, ew + 4096, eb + 64, e0w, e0b,
                                             xv3[1], xv4[1], wss);
    k_p1s<false><<<GRID, 256, 0, stream>>>(w16, ew + 8192, eb + 128, xv3[2], xv4[2],
                                           xv2[2], spread, pooled);
    k_finw<<<1, 64, 0, stream>>>(spread, ebng + 128, ebnb + 128, wss);
    k_last<<<GRID, 256, 0, stream>>>(w16, ew + 8192, eb + 128, xv3[2], xv4[2], wss,
                                     elw, elb, out);
}